// Round 13
// baseline (668.855 us; speedup 1.0000x reference)
//
#include <hip/hip_runtime.h>
#include <hip/hip_fp16.h>
#include <stdint.h>

typedef __attribute__((ext_vector_type(8))) short bf16x8;
typedef __attribute__((ext_vector_type(4))) float f32x4;
typedef __attribute__((ext_vector_type(4))) short short4v;

#define DEV __device__ __forceinline__
#define L2E 1.4426950408889634f

DEV float bf2f(unsigned short s){ union{unsigned int u; float f;} x; x.u = ((unsigned int)s)<<16; return x.f; }
DEV unsigned short f2bf(float f){ union{float f; unsigned int u;} x; x.f = f; x.u += 0x7fffu + ((x.u>>16)&1u); return (unsigned short)(x.u>>16); }
DEV float h2f(unsigned short u){ return __half2float(__ushort_as_half(u)); }
DEV unsigned short f2h(float f){ return __half_as_ushort(__float2half(f)); }

DEV f32x4 mfma16(bf16x8 a, bf16x8 b, f32x4 c){
  return __builtin_amdgcn_mfma_f32_16x16x32_bf16(a, b, c, 0, 0, 0);
}
DEV f32x4 zero4(){ f32x4 z; z[0]=0.f; z[1]=0.f; z[2]=0.f; z[3]=0.f; return z; }
DEV bf16x8 zerob(){ bf16x8 z; z[0]=0;z[1]=0;z[2]=0;z[3]=0;z[4]=0;z[5]=0;z[6]=0;z[7]=0; return z; }
DEV float fexp2(float x){ float r; asm volatile("v_exp_f32 %0, %1" : "=v"(r) : "v"(x)); return r; }
DEV void barw(){ asm volatile("s_waitcnt lgkmcnt(0)" ::: "memory"); __builtin_amdgcn_s_barrier(); }

// ---------------- elementwise f32 -> bf16 ----------------
__global__ __launch_bounds__(256) void k_f32_to_bf16(const float* __restrict__ in, unsigned short* __restrict__ out, int n4){
  int i = blockIdx.x*256 + threadIdx.x;
  if (i < n4){
    float4 v = ((const float4*)in)[i];
    short4v o; o.x=(short)f2bf(v.x); o.y=(short)f2bf(v.y); o.z=(short)f2bf(v.z); o.w=(short)f2bf(v.w);
    ((short4v*)out)[i] = o;
  }
}

// ------------- f32 [R][C] -> bf16 transposed [C][R] -------------
__global__ __launch_bounds__(256) void k_convT(const float* __restrict__ in, unsigned short* __restrict__ out, int R, int Cc){
  __shared__ float t[32][33];
  int c0 = blockIdx.x*32, r0 = blockIdx.y*32;
  int tid = threadIdx.x;
  int row = tid>>3, col4 = (tid&7)*4;
  float4 v = *(const float4*)&in[(size_t)(r0+row)*Cc + c0 + col4];
  t[row][col4+0]=v.x; t[row][col4+1]=v.y; t[row][col4+2]=v.z; t[row][col4+3]=v.w;
  __syncthreads();
  short4v o;
  o.x=(short)f2bf(t[col4+0][row]); o.y=(short)f2bf(t[col4+1][row]);
  o.z=(short)f2bf(t[col4+2][row]); o.w=(short)f2bf(t[col4+3][row]);
  *(short4v*)&out[(size_t)(c0+row)*R + r0 + col4] = o;
}

// ------------- small prep -------------
__global__ __launch_bounds__(256) void k_prep(const float* __restrict__ wpre, const float* __restrict__ wpost,
                                              const float* __restrict__ temp,
                                              unsigned short* __restrict__ wpre_t2,
                                              unsigned short* __restrict__ wpost_b){
  int t = threadIdx.x;
  float T = temp[0];
  wpre_t2[t] = f2bf(wpre[t]*T*L2E);
  wpost_b[t] = f2bf(wpost[t]);
}

// ------------- mask bytes -> f32 addend -------------
__global__ __launch_bounds__(256) void k_maskf(const unsigned char* __restrict__ mask, float* __restrict__ maskf){
  int i = blockIdx.x*256 + threadIdx.x;
  if (i < 4096) maskf[i] = mask[i] ? -1e30f : 0.f;
}

// ------------- pos_bias -> exp2(pb*L2E) fp16, permuted [i][j][g] -------------
__global__ __launch_bounds__(256) void k_pbexp(const float* __restrict__ pb, unsigned short* __restrict__ epb){
  int idx = blockIdx.x*256 + threadIdx.x;       // idx = i*2048 + j
  int i = idx >> 11, j = idx & 2047;
  unsigned int pk[8];
  #pragma unroll
  for (int g2=0; g2<8; ++g2){
    float a = fexp2(pb[(size_t)(2*g2  )*4194304 + (size_t)i*2048 + j] * L2E);
    float b = fexp2(pb[(size_t)(2*g2+1)*4194304 + (size_t)i*2048 + j] * L2E);
    pk[g2] = (unsigned int)f2h(a) | ((unsigned int)f2h(b)<<16);
  }
  uint4 o0, o1;
  o0.x=pk[0]; o0.y=pk[1]; o0.z=pk[2]; o0.w=pk[3];
  o1.x=pk[4]; o1.y=pk[5]; o1.z=pk[6]; o1.w=pk[7];
  *(uint4*)&epb[(size_t)idx*16]     = o0;
  *(uint4*)&epb[(size_t)idx*16 + 8] = o1;
}

// ------------- GEMM -------------
template<int OUTF>
__global__ __launch_bounds__(256,2) void k_gemm(const unsigned short* __restrict__ A, const unsigned short* __restrict__ Bt,
                                                void* __restrict__ Cv, int M, int Nn, int K){
  __shared__ unsigned short As[128][72];
  __shared__ unsigned short Bs[128][72];
  int tid = threadIdx.x;
  int n0 = blockIdx.x*128, m0 = blockIdx.y*128;
  int w = tid>>6, lane = tid&63, lg = lane>>4, lp = lane&15;
  int wm = (w>>1)*64, wn = (w&1)*64;
  f32x4 acc[4][4];
  #pragma unroll
  for (int i=0;i<4;++i)
    #pragma unroll
    for (int j=0;j<4;++j) acc[i][j] = zero4();

  for (int kt=0; kt<K; kt+=64){
    #pragma unroll
    for (int cch=0; cch<4; ++cch){
      int e = tid + cch*256; int r = e>>3, cl = (e&7)*8;
      *(bf16x8*)&As[r][cl] = *(const bf16x8*)&A[(size_t)(m0+r)*K + kt + cl];
      *(bf16x8*)&Bs[r][cl] = *(const bf16x8*)&Bt[(size_t)(n0+r)*K + kt + cl];
    }
    __syncthreads();
    #pragma unroll
    for (int ks=0; ks<2; ++ks){
      bf16x8 a[4], b[4];
      #pragma unroll
      for (int mi=0; mi<4; ++mi) a[mi] = *(const bf16x8*)&As[wm+mi*16+lp][ks*32 + lg*8];
      #pragma unroll
      for (int ni=0; ni<4; ++ni) b[ni] = *(const bf16x8*)&Bs[wn+ni*16+lp][ks*32 + lg*8];
      #pragma unroll
      for (int mi=0; mi<4; ++mi)
        #pragma unroll
        for (int ni=0; ni<4; ++ni)
          acc[mi][ni] = mfma16(a[mi], b[ni], acc[mi][ni]);
    }
    __syncthreads();
  }
  #pragma unroll
  for (int mi=0; mi<4; ++mi)
    #pragma unroll
    for (int ni=0; ni<4; ++ni)
      #pragma unroll
      for (int r=0; r<4; ++r){
        int row = m0+wm+mi*16+lg*4+r, col = n0+wn+ni*16+lp;
        if (OUTF) ((float*)Cv)[(size_t)row*Nn+col] = acc[mi][ni][r];
        else ((unsigned short*)Cv)[(size_t)row*Nn+col] = f2bf(acc[mi][ni][r]);
      }
}

// ------------- split qkv, l2norm q/k -------------
__global__ __launch_bounds__(256) void k_split_norm(const unsigned short* __restrict__ qkv,
                                                    unsigned short* __restrict__ q, unsigned short* __restrict__ k,
                                                    unsigned short* __restrict__ v, float* __restrict__ kv_out){
  int w = threadIdx.x>>6, lane = threadIdx.x&63;
  int widx = blockIdx.x*4 + w;
  int h = widx & 15; int bn = widx >> 4;
  int b = bn >> 11; int n = bn & 2047;
  size_t base = (size_t)bn*3072 + h*192 + lane*3;
  float qv = bf2f(qkv[base]), kvv = bf2f(qkv[base+1]), vv = bf2f(qkv[base+2]);
  float nq = qv*qv, nk = kvv*kvv;
  #pragma unroll
  for (int m=1; m<64; m<<=1){ nq += __shfl_xor(nq, m); nk += __shfl_xor(nk, m); }
  float qn = qv / fmaxf(sqrtf(nq), 1e-12f);
  float kn = kvv / fmaxf(sqrtf(nk), 1e-12f);
  size_t idx = ((size_t)(b*16+h)*2048 + n)*64 + lane;
  q[idx] = f2bf(qn); k[idx] = f2bf(kn); v[idx] = f2bf(vv);
  kv_out[idx] = kn;
  kv_out[4194304 + idx] = vv;
}

// ------------- v -> vt transposed -------------
__global__ __launch_bounds__(256) void k_transpose_v(const unsigned short* __restrict__ v, unsigned short* __restrict__ vt){
  __shared__ unsigned short t[64][72];
  int bh = blockIdx.y; int n0 = blockIdx.x*64;
  int tid = threadIdx.x;
  #pragma unroll
  for (int cch=0; cch<2; ++cch){
    int e = tid + cch*256; int r = e>>3, c8 = (e&7)*8;
    *(bf16x8*)&t[r][c8] = *(const bf16x8*)&v[((size_t)bh*2048 + n0 + r)*64 + c8];
  }
  __syncthreads();
  #pragma unroll
  for (int cch=0; cch<2; ++cch){
    int e = tid + cch*256; int d = e>>3, nn8 = (e&7)*8;
    bf16x8 o;
    #pragma unroll
    for (int i=0;i<8;++i) o[i] = (short)t[nn8+i][d];
    *(bf16x8*)&vt[((size_t)bh*64 + d)*2048 + n0 + nn8] = o;
  }
}

// ------------- vsum -------------
__global__ __launch_bounds__(256) void k_vsum(const unsigned short* __restrict__ v, float* __restrict__ vsum){
  int bg = blockIdx.x;
  int d = threadIdx.x & 63, part = threadIdx.x>>6;
  float s = 0.f;
  for (int n = part*512; n < part*512+512; ++n) s += bf2f(v[((size_t)bg*2048 + n)*64 + d]);
  __shared__ float red[4][64];
  red[part][d] = s; __syncthreads();
  if (part==0) vsum[bg*64 + d] = red[0][d]+red[1][d]+red[2][d]+red[3][d];
}

// =================================================================
// k_score2 (no launch_bounds): epb fp16 one tile ahead; S dbuf +
// 1 barrier/tile. Allocator free -> expect ~2 blocks/CU.
// =================================================================
__global__ void k_score2(
    const unsigned short* __restrict__ q,
    const unsigned short* __restrict__ kk,
    const unsigned short* __restrict__ epb,
    const float* __restrict__ maskf,
    const unsigned short* __restrict__ wpre_t2,
    const float* __restrict__ bpre,
    unsigned short* __restrict__ Pb,
    float* __restrict__ part_l)
{
  __shared__ __align__(16) char smem[40960];
  const int tid = threadIdx.x;
  const int w = tid>>6, lane = tid&63, lg = lane>>4, lp = lane&15;
  const int bid = blockIdx.x;
  const int qd = bid>>4, r2 = bid&15;
  const int b = r2>>3, n = qd*8 + (r2&7);
  const int it = n>>2, js = n&3;
  const int i0 = it*16, jsb = js*512;
  const int mbase = b*2048;

  bf16x8 qf[2][2];
  #pragma unroll
  for (int hh=0; hh<2; ++hh){
    const unsigned short* qb = q + ((size_t)(b*16+2*w+hh)*2048 + i0 + lp)*64;
    qf[hh][0] = *(const bf16x8*)(qb + lg*8);
    qf[hh][1] = *(const bf16x8*)(qb + 32 + lg*8);
  }
  bf16x8 preA = zerob();
  if (lg < 2) preA = *(const bf16x8*)&wpre_t2[lp*16 + lg*8];
  float bpre_s[4];
  #pragma unroll
  for (int r=0;r<4;++r) bpre_s[r] = bpre[lg*4+r]*L2E - 32.0f;

  float sacc[2][4];
  #pragma unroll
  for (int ii=0;ii<2;++ii)
    #pragma unroll
    for (int r=0;r<4;++r) sacc[ii][r] = 0.f;

  const size_t kbase0 = (size_t)(b*16 + 2*w)*131072;
  const size_t kbase1 = (size_t)(b*16 + 2*w+1)*131072;

  // prefetch K(0), ep(0), mk(0)
  bf16x8 k0v[4], k1v[4];
  #pragma unroll
  for (int kf=0; kf<2; ++kf)
    #pragma unroll
    for (int jf=0; jf<2; ++jf){
      size_t off = (size_t)(jsb + jf*16 + lp)*64 + kf*32 + lg*8;
      k0v[kf*2+jf] = *(const bf16x8*)(kk + kbase0 + off);
      k1v[kf*2+jf] = *(const bf16x8*)(kk + kbase1 + off);
    }
  short4v epA[4], epB[4];
  float mkA0, mkA1, mkB0, mkB1;
  #pragma unroll
  for (int cc=0; cc<4; ++cc){
    int il = 2*w + (cc>>1);
    epA[cc] = *(const short4v*)&epb[(((size_t)(i0+il)*2048) + jsb + (cc&1)*16 + lp)*16 + lg*4];
  }
  mkA0 = maskf[mbase + jsb + lp];
  mkA1 = maskf[mbase + jsb + 16 + lp];

  for (int tt=0; tt<8; ++tt){
    // ===== TILE EVEN: consume epA/mkA, prefetch epB/mkB =====
    {
      const int j0 = jsb + (2*tt)*32;
      const int j1 = jsb + (2*tt+1)*32;
      char* sbuf = smem;
      f32x4 s0[2], s1[2];
      #pragma unroll
      for (int jf=0;jf<2;++jf){ s0[jf]=zero4(); s1[jf]=zero4(); }
      #pragma unroll
      for (int kf=0; kf<2; ++kf)
        #pragma unroll
        for (int jf=0; jf<2; ++jf){
          s0[jf] = mfma16(qf[0][kf], k0v[kf*2+jf], s0[jf]);
          s1[jf] = mfma16(qf[1][kf], k1v[kf*2+jf], s1[jf]);
        }
      #pragma unroll
      for (int jf=0;jf<2;++jf)
        #pragma unroll
        for (int r=0;r<4;++r){
          int ij = (lg*4+r)*32 + jf*16 + lp;
          unsigned int pk = (unsigned int)f2bf(s0[jf][r]) | ((unsigned int)f2bf(s1[jf][r])<<16);
          *(unsigned int*)(sbuf + ij*40 + w*4) = pk;
        }
      #pragma unroll
      for (int kf=0; kf<2; ++kf)
        #pragma unroll
        for (int jf=0; jf<2; ++jf){
          size_t off = (size_t)(j1 + jf*16 + lp)*64 + kf*32 + lg*8;
          k0v[kf*2+jf] = *(const bf16x8*)(kk + kbase0 + off);
          k1v[kf*2+jf] = *(const bf16x8*)(kk + kbase1 + off);
        }
      #pragma unroll
      for (int cc=0; cc<4; ++cc){
        int il = 2*w + (cc>>1);
        epB[cc] = *(const short4v*)&epb[(((size_t)(i0+il)*2048) + j1 + (cc&1)*16 + lp)*16 + lg*4];
      }
      mkB0 = maskf[mbase + j1 + lp];
      mkB1 = maskf[mbase + j1 + 16 + lp];
      barw();
      #pragma unroll
      for (int cc=0; cc<4; ++cc){
        int c = w*4+cc;
        int il = 2*w + (cc>>1);
        int jl = (cc&1)*16 + lp;
        bf16x8 sfrag = zerob();
        if (lg < 2) sfrag = *(const bf16x8*)(sbuf + (c*16+lp)*40 + lg*16);
        f32x4 pa = mfma16(preA, sfrag, zero4());
        float mkj = (cc&1) ? mkA1 : mkA0;
        float pv0 = fexp2(pa[0] + bpre_s[0] + mkj) * h2f((unsigned short)epA[cc][0]);
        float pv1 = fexp2(pa[1] + bpre_s[1] + mkj) * h2f((unsigned short)epA[cc][1]);
        float pv2 = fexp2(pa[2] + bpre_s[2] + mkj) * h2f((unsigned short)epA[cc][2]);
        float pv3 = fexp2(pa[3] + bpre_s[3] + mkj) * h2f((unsigned short)epA[cc][3]);
        sacc[cc>>1][0] += pv0; sacc[cc>>1][1] += pv1;
        sacc[cc>>1][2] += pv2; sacc[cc>>1][3] += pv3;
        short4v p4;
        p4.x = (short)f2bf(pv0); p4.y = (short)f2bf(pv1);
        p4.z = (short)f2bf(pv2); p4.w = (short)f2bf(pv3);
        *(short4v*)&Pb[(((size_t)(b*2048 + i0+il)*2048) + j0 + jl)*16 + lg*4] = p4;
      }
    }
    // ===== TILE ODD: consume epB/mkB, prefetch epA/mkA =====
    {
      const int j0 = jsb + (2*tt+1)*32;
      const int j1 = jsb + ((2*tt+2)&15)*32;
      char* sbuf = smem + 20480;
      f32x4 s0[2], s1[2];
      #pragma unroll
      for (int jf=0;jf<2;++jf){ s0[jf]=zero4(); s1[jf]=zero4(); }
      #pragma unroll
      for (int kf=0; kf<2; ++kf)
        #pragma unroll
        for (int jf=0; jf<2; ++jf){
          s0[jf] = mfma16(qf[0][kf], k0v[kf*2+jf], s0[jf]);
          s1[jf] = mfma16(qf[1][kf], k1v[kf*2+jf], s1[jf]);
        }
      #pragma unroll
      for (int jf=0;jf<2;++jf)
        #pragma unroll
        for (int r=0;r<4;++r){
          int ij = (lg*4+r)*32 + jf*16 + lp;
          unsigned int pk = (unsigned int)f2bf(s0[jf][r]) | ((unsigned int)f2bf(s1[jf][r])<<16);
          *(unsigned int*)(sbuf + ij*40 + w*4) = pk;
        }
      #pragma unroll
      for (int kf=0; kf<2; ++kf)
        #pragma unroll
        for (int jf=0; jf<2; ++jf){
          size_t off = (size_t)(j1 + jf*16 + lp)*64 + kf*32 + lg*8;
          k0v[kf*2+jf] = *(const bf16x8*)(kk + kbase0 + off);
          k1v[kf*2+jf] = *(const bf16x8*)(kk + kbase1 + off);
        }
      #pragma unroll
      for (int cc=0; cc<4; ++cc){
        int il = 2*w + (cc>>1);
        epA[cc] = *(const short4v*)&epb[(((size_t)(i0+il)*2048) + j1 + (cc&1)*16 + lp)*16 + lg*4];
      }
      mkA0 = maskf[mbase + j1 + lp];
      mkA1 = maskf[mbase + j1 + 16 + lp];
      barw();
      #pragma unroll
      for (int cc=0; cc<4; ++cc){
        int c = w*4+cc;
        int il = 2*w + (cc>>1);
        int jl = (cc&1)*16 + lp;
        bf16x8 sfrag = zerob();
        if (lg < 2) sfrag = *(const bf16x8*)(sbuf + (c*16+lp)*40 + lg*16);
        f32x4 pa = mfma16(preA, sfrag, zero4());
        float mkj = (cc&1) ? mkB1 : mkB0;
        float pv0 = fexp2(pa[0] + bpre_s[0] + mkj) * h2f((unsigned short)epB[cc][0]);
        float pv1 = fexp2(pa[1] + bpre_s[1] + mkj) * h2f((unsigned short)epB[cc][1]);
        float pv2 = fexp2(pa[2] + bpre_s[2] + mkj) * h2f((unsigned short)epB[cc][2]);
        float pv3 = fexp2(pa[3] + bpre_s[3] + mkj) * h2f((unsigned short)epB[cc][3]);
        sacc[cc>>1][0] += pv0; sacc[cc>>1][1] += pv1;
        sacc[cc>>1][2] += pv2; sacc[cc>>1][3] += pv3;
        short4v p4;
        p4.x = (short)f2bf(pv0); p4.y = (short)f2bf(pv1);
        p4.z = (short)f2bf(pv2); p4.w = (short)f2bf(pv3);
        *(short4v*)&Pb[(((size_t)(b*2048 + i0+il)*2048) + j0 + jl)*16 + lg*4] = p4;
      }
    }
  }

  #pragma unroll
  for (int ii=0;ii<2;++ii)
    #pragma unroll
    for (int r=0;r<4;++r){
      float v = sacc[ii][r];
      #pragma unroll
      for (int m=1; m<16; m<<=1) v += __shfl_xor(v, m);
      sacc[ii][r] = v;
    }
  if (lp == 0){
    int base = ((b*128+it)*4 + js)*256;
    #pragma unroll
    for (int ii=0;ii<2;++ii){
      float4 st; st.x = sacc[ii][0]; st.y = sacc[ii][1]; st.z = sacc[ii][2]; st.w = sacc[ii][3];
      *(float4*)&part_l[base + (2*w+ii)*16 + lg*4] = st;
    }
  }
}

// =================================================================
// k_mix: round-8 proven version (Al dbuf, 1 barrier/tile, (512,4))
// =================================================================
__global__ __launch_bounds__(512,4) void k_mix(
    const unsigned short* __restrict__ Pb,
    const unsigned short* __restrict__ vt,
    const unsigned short* __restrict__ wpost_b,
    const float* __restrict__ bpost,
    const float* __restrict__ vsum,
    const float* __restrict__ part_l,
    float* __restrict__ pout0,
    float* __restrict__ pout1)
{
  __shared__ __align__(16) char smem[33792];
  float* linv = (float*)(smem + 32768);
  const int tid = threadIdx.x;
  const int w = tid>>6, lane = tid&63, lg = lane>>4, lp = lane&15;
  const int bid = blockIdx.x;
  const int qd = bid>>4, r2 = bid&15;
  const int b = r2>>3, n = qd*8 + (r2&7);
  const int it = n>>1, js = n&1;
  const int i0 = it*16, jsb = js*1024;

  if (tid < 256){
    int base = ((b*128+it)*4)*256 + tid;
    float sum = part_l[base] + part_l[base+256] + part_l[base+512] + part_l[base+768];
    linv[tid] = 1.f/sum;
  }
  __syncthreads();

  bf16x8 postB[2];
  #pragma unroll
  for (int ii=0;ii<2;++ii){
    postB[ii] = zerob();
    if (lg < 2){
      bf16x8 wf = *(const bf16x8*)&wpost_b[lp*16 + lg*8];
      int i = 2*w+ii;
      #pragma unroll
      for (int e=0;e<8;++e){
        float vsc = bf2f((unsigned short)wf[e]) * linv[i*16 + lg*8 + e];
        postB[ii][e] = (short)f2bf(vsc);
      }
    }
  }

  f32x4 oacc[2][4];
  #pragma unroll
  for (int hh=0; hh<2; ++hh)
    #pragma unroll
    for (int df=0; df<4; ++df) oacc[hh][df] = zero4();

  __syncthreads();

  for (int t=0; t<32; ++t){
    const int j0 = jsb + t*32;
    char* abuf = smem + (t&1)*16384;
    bf16x8 pfr[4];
    #pragma unroll
    for (int cc=0; cc<4; ++cc){
      int il = 2*w + (cc>>1);
      pfr[cc] = zerob();
      if (lg < 2)
        pfr[cc] = *(const bf16x8*)&Pb[(((size_t)(b*2048 + i0+il)*2048) + j0 + (cc&1)*16 + lp)*16 + lg*8];
    }
    bf16x8 vfr[2][4];
    #pragma unroll
    for (int hh=0; hh<2; ++hh)
      #pragma unroll
      for (int df=0; df<4; ++df)
        vfr[hh][df] = *(const bf16x8*)(vt + ((size_t)(b*16+2*w+hh)*64 + df*16 + lp)*2048 + j0 + lg*8);
    #pragma unroll
    for (int cc=0; cc<4; ++cc){
      int il = 2*w + (cc>>1);
      f32x4 aa = mfma16(pfr[cc], postB[cc>>1], zero4());
      short4v av;
      av.x = (short)f2bf(aa[0]); av.y = (short)f2bf(aa[1]);
      av.z = (short)f2bf(aa[2]); av.w = (short)f2bf(aa[3]);
      int row = lp*16 + il;
      int chunk = ((cc&1)*4 + lg) ^ ((lp ^ il)&6);
      *(short4v*)(abuf + row*64 + chunk*8) = av;
    }
    barw();
    #pragma unroll
    for (int hh=0; hh<2; ++hh){
      int gg = 2*w+hh;
      bf16x8 af = *(const bf16x8*)(abuf + (gg*16+lp)*64 + (((lg*2) ^ ((gg^lp)&6))*8));
      #pragma unroll
      for (int df=0; df<4; ++df)
        oacc[hh][df] = mfma16(af, vfr[hh][df], oacc[hh][df]);
    }
  }

  float* po = js ? pout1 : pout0;
  #pragma unroll
  for (int hh=0; hh<2; ++hh){
    int gg = 2*w+hh;
    float bp = (js==0) ? bpost[gg] : 0.f;
    #pragma unroll
    for (int df=0; df<4; ++df){
      int d = df*16+lp;
      float vs = vsum[(b*16+gg)*64 + d];
      #pragma unroll
      for (int r=0;r<4;++r){
        po[((size_t)b*2048 + i0 + lg*4 + r)*1024 + gg*64 + d] = oacc[hh][df][r] + bp*vs;
      }
    }
  }
}

// ------------- combine partial outputs -> bf16 attn_out -------------
__global__ __launch_bounds__(256) void k_combine(const float* __restrict__ p0, const float* __restrict__ p1,
                                                 unsigned short* __restrict__ ao){
  int i = blockIdx.x*256 + threadIdx.x;
  float4 a = ((const float4*)p0)[i];
  float4 c = ((const float4*)p1)[i];
  short4v o;
  o.x=(short)f2bf(a.x+c.x); o.y=(short)f2bf(a.y+c.y);
  o.z=(short)f2bf(a.z+c.z); o.w=(short)f2bf(a.w+c.w);
  ((short4v*)ao)[i] = o;
}

// ======================================================================
extern "C" void kernel_launch(void* const* d_in, const int* in_sizes, int n_in,
                              void* d_out, int out_size, void* d_ws, size_t ws_size,
                              hipStream_t stream)
{
  const float* x        = (const float*)d_in[0];
  const float* pos_bias = (const float*)d_in[1];
  const unsigned char* mask = (const unsigned char*)d_in[2];
  const float* Wqkv     = (const float*)d_in[3];
  const float* Wout     = (const float*)d_in[4];
  const float* Wpre     = (const float*)d_in[5];
  const float* bpre     = (const float*)d_in[6];
  const float* Wpost    = (const float*)d_in[7];
  const float* bpost    = (const float*)d_in[8];
  const float* temp     = (const float*)d_in[9];
  float* out = (float*)d_out;
  float* kv_out = out + 4194304;

  char* ws = (char*)d_ws;
  unsigned short* XB    = (unsigned short*)(ws + 0);
  unsigned short* WT    = (unsigned short*)(ws + 8388608);
  unsigned short* WOT   = (unsigned short*)(ws + 8388608);
  float*          PART_L= (float*)        (ws + 11534336);
  unsigned short* WPRE2 = (unsigned short*)(ws + 12583424);
  unsigned short* WPOST = (unsigned short*)(ws + 12583936);
  float*          VSUM  = (float*)        (ws + 12584448);
  float*          MASKF = (float*)        (ws + 12593152);
  unsigned short* QKV   = (unsigned short*)(ws + 14680064);
  unsigned short* VT    = (unsigned short*)(ws + 14680064);
  float*          POUT0 = (float*)        (ws + 23068672);
  unsigned short* Q     = (unsigned short*)(ws + 39845888);
  unsigned short* KB    = (unsigned short*)(ws + 48234496);
  unsigned short* VB    = (unsigned short*)(ws + 56623104);
  float*          POUT1 = (float*)        (ws + 56623104);
  unsigned short* PB    = (unsigned short*)(ws + 75497472);   // 268.4 MB
  unsigned short* EPB   = (unsigned short*)(ws + 343932928);  // 134.2 MB
  unsigned short* AO    = XB;

  k_f32_to_bf16<<<4096, 256, 0, stream>>>(x, XB, 1048576);
  k_convT<<<dim3(96,32), 256, 0, stream>>>(Wqkv, WT, 1024, 3072);
  k_gemm<0><<<dim3(24,32), 256, 0, stream>>>(XB, WT, (void*)QKV, 4096, 3072, 1024);
  k_split_norm<<<16384, 256, 0, stream>>>(QKV, Q, KB, VB, kv_out);
  k_transpose_v<<<dim3(32,32), 256, 0, stream>>>(VB, VT);
  k_vsum<<<32, 256, 0, stream>>>(VB, VSUM);
  k_prep<<<1, 256, 0, stream>>>(Wpre, Wpost, temp, WPRE2, WPOST);
  k_maskf<<<16, 256, 0, stream>>>(mask, MASKF);
  k_convT<<<dim3(32,32), 256, 0, stream>>>(Wout, WOT, 1024, 1024);

  k_pbexp<<<16384, 256, 0, stream>>>(pos_bias, EPB);
  k_score2<<<1024, 512, 0, stream>>>(Q, KB, EPB, MASKF, WPRE2, bpre, PB, PART_L);
  k_mix<<<512, 512, 0, stream>>>(PB, VT, WPOST, bpost, VSUM, PART_L, POUT0, POUT1);
  k_combine<<<4096, 256, 0, stream>>>(POUT0, POUT1, AO);
  k_gemm<1><<<dim3(8,32), 256, 0, stream>>>(AO, WOT, d_out, 4096, 1024, 1024);
}

// Round 14
// 580.262 us; speedup vs baseline: 1.1527x; 1.1527x over previous
//
#include <hip/hip_runtime.h>
#include <hip/hip_fp16.h>
#include <stdint.h>

typedef __attribute__((ext_vector_type(8))) short bf16x8;
typedef __attribute__((ext_vector_type(4))) float f32x4;
typedef __attribute__((ext_vector_type(4))) short short4v;

#define DEV __device__ __forceinline__
#define L2E 1.4426950408889634f

DEV float bf2f(unsigned short s){ union{unsigned int u; float f;} x; x.u = ((unsigned int)s)<<16; return x.f; }
DEV unsigned short f2bf(float f){ union{float f; unsigned int u;} x; x.f = f; x.u += 0x7fffu + ((x.u>>16)&1u); return (unsigned short)(x.u>>16); }
DEV float h2f(unsigned short u){ return __half2float(__ushort_as_half(u)); }
DEV unsigned short f2h(float f){ return __half_as_ushort(__float2half(f)); }

DEV f32x4 mfma16(bf16x8 a, bf16x8 b, f32x4 c){
  return __builtin_amdgcn_mfma_f32_16x16x32_bf16(a, b, c, 0, 0, 0);
}
DEV f32x4 zero4(){ f32x4 z; z[0]=0.f; z[1]=0.f; z[2]=0.f; z[3]=0.f; return z; }
DEV bf16x8 zerob(){ bf16x8 z; z[0]=0;z[1]=0;z[2]=0;z[3]=0;z[4]=0;z[5]=0;z[6]=0;z[7]=0; return z; }
DEV float fexp2(float x){ float r; asm volatile("v_exp_f32 %0, %1" : "=v"(r) : "v"(x)); return r; }
DEV void barw(){ asm volatile("s_waitcnt lgkmcnt(0)" ::: "memory"); __builtin_amdgcn_s_barrier(); }

// ---------------- elementwise f32 -> bf16 ----------------
__global__ __launch_bounds__(256) void k_f32_to_bf16(const float* __restrict__ in, unsigned short* __restrict__ out, int n4){
  int i = blockIdx.x*256 + threadIdx.x;
  if (i < n4){
    float4 v = ((const float4*)in)[i];
    short4v o; o.x=(short)f2bf(v.x); o.y=(short)f2bf(v.y); o.z=(short)f2bf(v.z); o.w=(short)f2bf(v.w);
    ((short4v*)out)[i] = o;
  }
}

// ------------- f32 [R][C] -> bf16 transposed [C][R] -------------
__global__ __launch_bounds__(256) void k_convT(const float* __restrict__ in, unsigned short* __restrict__ out, int R, int Cc){
  __shared__ float t[32][33];
  int c0 = blockIdx.x*32, r0 = blockIdx.y*32;
  int tid = threadIdx.x;
  int row = tid>>3, col4 = (tid&7)*4;
  float4 v = *(const float4*)&in[(size_t)(r0+row)*Cc + c0 + col4];
  t[row][col4+0]=v.x; t[row][col4+1]=v.y; t[row][col4+2]=v.z; t[row][col4+3]=v.w;
  __syncthreads();
  short4v o;
  o.x=(short)f2bf(t[col4+0][row]); o.y=(short)f2bf(t[col4+1][row]);
  o.z=(short)f2bf(t[col4+2][row]); o.w=(short)f2bf(t[col4+3][row]);
  *(short4v*)&out[(size_t)(c0+row)*R + r0 + col4] = o;
}

// ------------- small prep -------------
__global__ __launch_bounds__(256) void k_prep(const float* __restrict__ wpre, const float* __restrict__ wpost,
                                              const float* __restrict__ temp,
                                              unsigned short* __restrict__ wpre_t2,
                                              unsigned short* __restrict__ wpost_b){
  int t = threadIdx.x;
  float T = temp[0];
  wpre_t2[t] = f2bf(wpre[t]*T*L2E);
  wpost_b[t] = f2bf(wpost[t]);
}

// ------------- mask bytes -> f32 addend -------------
__global__ __launch_bounds__(256) void k_maskf(const unsigned char* __restrict__ mask, float* __restrict__ maskf){
  int i = blockIdx.x*256 + threadIdx.x;
  if (i < 4096) maskf[i] = mask[i] ? -1e30f : 0.f;
}

// ------------- pos_bias -> exp2(pb*L2E) fp16, permuted [i][j][g] -------------
// float4 version: each thread handles 4 consecutive j for all 16 g.
__global__ __launch_bounds__(256) void k_pbexp(const float* __restrict__ pb, unsigned short* __restrict__ epb){
  int idx = blockIdx.x*256 + threadIdx.x;       // idx -> (i, j4): 1M threads
  int i = idx >> 9, j4 = (idx & 511)*4;
  float4 v[16];
  #pragma unroll
  for (int g=0; g<16; ++g)
    v[g] = *(const float4*)&pb[(size_t)g*4194304 + (size_t)i*2048 + j4];
  #pragma unroll
  for (int jj=0; jj<4; ++jj){
    unsigned int pk[8];
    #pragma unroll
    for (int g2=0; g2<8; ++g2){
      float a = fexp2(((const float*)&v[2*g2  ])[jj] * L2E);
      float b = fexp2(((const float*)&v[2*g2+1])[jj] * L2E);
      pk[g2] = (unsigned int)f2h(a) | ((unsigned int)f2h(b)<<16);
    }
    uint4 o0, o1;
    o0.x=pk[0]; o0.y=pk[1]; o0.z=pk[2]; o0.w=pk[3];
    o1.x=pk[4]; o1.y=pk[5]; o1.z=pk[6]; o1.w=pk[7];
    *(uint4*)&epb[((size_t)idx*4 + jj)*16]     = o0;
    *(uint4*)&epb[((size_t)idx*4 + jj)*16 + 8] = o1;
  }
}

// ------------- GEMM -------------
template<int OUTF>
__global__ __launch_bounds__(256,2) void k_gemm(const unsigned short* __restrict__ A, const unsigned short* __restrict__ Bt,
                                                void* __restrict__ Cv, int M, int Nn, int K){
  __shared__ unsigned short As[128][72];
  __shared__ unsigned short Bs[128][72];
  int tid = threadIdx.x;
  int n0 = blockIdx.x*128, m0 = blockIdx.y*128;
  int w = tid>>6, lane = tid&63, lg = lane>>4, lp = lane&15;
  int wm = (w>>1)*64, wn = (w&1)*64;
  f32x4 acc[4][4];
  #pragma unroll
  for (int i=0;i<4;++i)
    #pragma unroll
    for (int j=0;j<4;++j) acc[i][j] = zero4();

  for (int kt=0; kt<K; kt+=64){
    #pragma unroll
    for (int cch=0; cch<4; ++cch){
      int e = tid + cch*256; int r = e>>3, cl = (e&7)*8;
      *(bf16x8*)&As[r][cl] = *(const bf16x8*)&A[(size_t)(m0+r)*K + kt + cl];
      *(bf16x8*)&Bs[r][cl] = *(const bf16x8*)&Bt[(size_t)(n0+r)*K + kt + cl];
    }
    __syncthreads();
    #pragma unroll
    for (int ks=0; ks<2; ++ks){
      bf16x8 a[4], b[4];
      #pragma unroll
      for (int mi=0; mi<4; ++mi) a[mi] = *(const bf16x8*)&As[wm+mi*16+lp][ks*32 + lg*8];
      #pragma unroll
      for (int ni=0; ni<4; ++ni) b[ni] = *(const bf16x8*)&Bs[wn+ni*16+lp][ks*32 + lg*8];
      #pragma unroll
      for (int mi=0; mi<4; ++mi)
        #pragma unroll
        for (int ni=0; ni<4; ++ni)
          acc[mi][ni] = mfma16(a[mi], b[ni], acc[mi][ni]);
    }
    __syncthreads();
  }
  #pragma unroll
  for (int mi=0; mi<4; ++mi)
    #pragma unroll
    for (int ni=0; ni<4; ++ni)
      #pragma unroll
      for (int r=0; r<4; ++r){
        int row = m0+wm+mi*16+lg*4+r, col = n0+wn+ni*16+lp;
        if (OUTF) ((float*)Cv)[(size_t)row*Nn+col] = acc[mi][ni][r];
        else ((unsigned short*)Cv)[(size_t)row*Nn+col] = f2bf(acc[mi][ni][r]);
      }
}

// ------------- split qkv, l2norm q/k -------------
__global__ __launch_bounds__(256) void k_split_norm(const unsigned short* __restrict__ qkv,
                                                    unsigned short* __restrict__ q, unsigned short* __restrict__ k,
                                                    unsigned short* __restrict__ v, float* __restrict__ kv_out){
  int w = threadIdx.x>>6, lane = threadIdx.x&63;
  int widx = blockIdx.x*4 + w;
  int h = widx & 15; int bn = widx >> 4;
  int b = bn >> 11; int n = bn & 2047;
  size_t base = (size_t)bn*3072 + h*192 + lane*3;
  float qv = bf2f(qkv[base]), kvv = bf2f(qkv[base+1]), vv = bf2f(qkv[base+2]);
  float nq = qv*qv, nk = kvv*kvv;
  #pragma unroll
  for (int m=1; m<64; m<<=1){ nq += __shfl_xor(nq, m); nk += __shfl_xor(nk, m); }
  float qn = qv / fmaxf(sqrtf(nq), 1e-12f);
  float kn = kvv / fmaxf(sqrtf(nk), 1e-12f);
  size_t idx = ((size_t)(b*16+h)*2048 + n)*64 + lane;
  q[idx] = f2bf(qn); k[idx] = f2bf(kn); v[idx] = f2bf(vv);
  kv_out[idx] = kn;
  kv_out[4194304 + idx] = vv;
}

// ------------- v -> vt transposed -------------
__global__ __launch_bounds__(256) void k_transpose_v(const unsigned short* __restrict__ v, unsigned short* __restrict__ vt){
  __shared__ unsigned short t[64][72];
  int bh = blockIdx.y; int n0 = blockIdx.x*64;
  int tid = threadIdx.x;
  #pragma unroll
  for (int cch=0; cch<2; ++cch){
    int e = tid + cch*256; int r = e>>3, c8 = (e&7)*8;
    *(bf16x8*)&t[r][c8] = *(const bf16x8*)&v[((size_t)bh*2048 + n0 + r)*64 + c8];
  }
  __syncthreads();
  #pragma unroll
  for (int cch=0; cch<2; ++cch){
    int e = tid + cch*256; int d = e>>3, nn8 = (e&7)*8;
    bf16x8 o;
    #pragma unroll
    for (int i=0;i<8;++i) o[i] = (short)t[nn8+i][d];
    *(bf16x8*)&vt[((size_t)bh*64 + d)*2048 + n0 + nn8] = o;
  }
}

// ------------- vsum -------------
__global__ __launch_bounds__(256) void k_vsum(const unsigned short* __restrict__ v, float* __restrict__ vsum){
  int bg = blockIdx.x;
  int d = threadIdx.x & 63, part = threadIdx.x>>6;
  float s = 0.f;
  for (int n = part*512; n < part*512+512; ++n) s += bf2f(v[((size_t)bg*2048 + n)*64 + d]);
  __shared__ float red[4][64];
  red[part][d] = s; __syncthreads();
  if (part==0) vsum[bg*64 + d] = red[0][d]+red[1][d]+red[2][d]+red[3][d];
}

// =================================================================
// k_score2 @ (512,4): ep (fp16 [i][j][g], contiguous) + mask loaded
// IN-TILE (low reg pressure, fits 64-reg cap); K one-ahead;
// S dbuf + 1 barrier/tile. grid 1024.
// =================================================================
__global__ __launch_bounds__(512,4) void k_score2(
    const unsigned short* __restrict__ q,
    const unsigned short* __restrict__ kk,
    const unsigned short* __restrict__ epb,
    const float* __restrict__ maskf,
    const unsigned short* __restrict__ wpre_t2,
    const float* __restrict__ bpre,
    unsigned short* __restrict__ Pb,
    float* __restrict__ part_l)
{
  __shared__ __align__(16) char smem[40960];
  const int tid = threadIdx.x;
  const int w = tid>>6, lane = tid&63, lg = lane>>4, lp = lane&15;
  const int bid = blockIdx.x;
  const int qd = bid>>4, r2 = bid&15;
  const int b = r2>>3, n = qd*8 + (r2&7);
  const int it = n>>2, js = n&3;
  const int i0 = it*16, jsb = js*512;
  const int mbase = b*2048;

  bf16x8 qf[2][2];
  #pragma unroll
  for (int hh=0; hh<2; ++hh){
    const unsigned short* qb = q + ((size_t)(b*16+2*w+hh)*2048 + i0 + lp)*64;
    qf[hh][0] = *(const bf16x8*)(qb + lg*8);
    qf[hh][1] = *(const bf16x8*)(qb + 32 + lg*8);
  }
  bf16x8 preA = zerob();
  if (lg < 2) preA = *(const bf16x8*)&wpre_t2[lp*16 + lg*8];
  float bpre_s[4];
  #pragma unroll
  for (int r=0;r<4;++r) bpre_s[r] = bpre[lg*4+r]*L2E - 32.0f;

  float sacc[2][4];
  #pragma unroll
  for (int ii=0;ii<2;++ii)
    #pragma unroll
    for (int r=0;r<4;++r) sacc[ii][r] = 0.f;

  const size_t kbase0 = (size_t)(b*16 + 2*w)*131072;
  const size_t kbase1 = (size_t)(b*16 + 2*w+1)*131072;

  // prefetch K(0)
  bf16x8 k0v[4], k1v[4];
  #pragma unroll
  for (int kf=0; kf<2; ++kf)
    #pragma unroll
    for (int jf=0; jf<2; ++jf){
      size_t off = (size_t)(jsb + jf*16 + lp)*64 + kf*32 + lg*8;
      k0v[kf*2+jf] = *(const bf16x8*)(kk + kbase0 + off);
      k1v[kf*2+jf] = *(const bf16x8*)(kk + kbase1 + off);
    }

  for (int t=0; t<16; ++t){
    const int j0 = jsb + t*32;
    const int j0n = jsb + ((t+1)&15)*32;
    char* sbuf = smem + (t&1)*20480;

    // this tile's ep + mask (issued first; consumed after barrier)
    short4v ept[4];
    #pragma unroll
    for (int cc=0; cc<4; ++cc){
      int il = 2*w + (cc>>1);
      ept[cc] = *(const short4v*)&epb[(((size_t)(i0+il)*2048) + j0 + (cc&1)*16 + lp)*16 + lg*4];
    }
    float mk0 = maskf[mbase + j0 + lp];
    float mk1 = maskf[mbase + j0 + 16 + lp];

    // QK (K prefetched last tile)
    f32x4 s0[2], s1[2];
    #pragma unroll
    for (int jf=0;jf<2;++jf){ s0[jf]=zero4(); s1[jf]=zero4(); }
    #pragma unroll
    for (int kf=0; kf<2; ++kf)
      #pragma unroll
      for (int jf=0; jf<2; ++jf){
        s0[jf] = mfma16(qf[0][kf], k0v[kf*2+jf], s0[jf]);
        s1[jf] = mfma16(qf[1][kf], k1v[kf*2+jf], s1[jf]);
      }
    // S write (40B rows)
    #pragma unroll
    for (int jf=0;jf<2;++jf)
      #pragma unroll
      for (int r=0;r<4;++r){
        int ij = (lg*4+r)*32 + jf*16 + lp;
        unsigned int pk = (unsigned int)f2bf(s0[jf][r]) | ((unsigned int)f2bf(s1[jf][r])<<16);
        *(unsigned int*)(sbuf + ij*40 + w*4) = pk;
      }
    // K prefetch next tile
    #pragma unroll
    for (int kf=0; kf<2; ++kf)
      #pragma unroll
      for (int jf=0; jf<2; ++jf){
        size_t off = (size_t)(j0n + jf*16 + lp)*64 + kf*32 + lg*8;
        k0v[kf*2+jf] = *(const bf16x8*)(kk + kbase0 + off);
        k1v[kf*2+jf] = *(const bf16x8*)(kk + kbase1 + off);
      }
    barw();   // single barrier per tile (S dbuf)

    // premix + exp2*ep + Pb store
    #pragma unroll
    for (int cc=0; cc<4; ++cc){
      int c = w*4+cc;
      int il = 2*w + (cc>>1);
      int jl = (cc&1)*16 + lp;
      bf16x8 sfrag = zerob();
      if (lg < 2) sfrag = *(const bf16x8*)(sbuf + (c*16+lp)*40 + lg*16);
      f32x4 pa = mfma16(preA, sfrag, zero4());
      float mkj = (cc&1) ? mk1 : mk0;
      float pv0 = fexp2(pa[0] + bpre_s[0] + mkj) * h2f((unsigned short)ept[cc][0]);
      float pv1 = fexp2(pa[1] + bpre_s[1] + mkj) * h2f((unsigned short)ept[cc][1]);
      float pv2 = fexp2(pa[2] + bpre_s[2] + mkj) * h2f((unsigned short)ept[cc][2]);
      float pv3 = fexp2(pa[3] + bpre_s[3] + mkj) * h2f((unsigned short)ept[cc][3]);
      sacc[cc>>1][0] += pv0; sacc[cc>>1][1] += pv1;
      sacc[cc>>1][2] += pv2; sacc[cc>>1][3] += pv3;
      short4v p4;
      p4.x = (short)f2bf(pv0); p4.y = (short)f2bf(pv1);
      p4.z = (short)f2bf(pv2); p4.w = (short)f2bf(pv3);
      *(short4v*)&Pb[(((size_t)(b*2048 + i0+il)*2048) + j0 + jl)*16 + lg*4] = p4;
    }
  }

  #pragma unroll
  for (int ii=0;ii<2;++ii)
    #pragma unroll
    for (int r=0;r<4;++r){
      float v = sacc[ii][r];
      #pragma unroll
      for (int m=1; m<16; m<<=1) v += __shfl_xor(v, m);
      sacc[ii][r] = v;
    }
  if (lp == 0){
    int base = ((b*128+it)*4 + js)*256;
    #pragma unroll
    for (int ii=0;ii<2;++ii){
      float4 st; st.x = sacc[ii][0]; st.y = sacc[ii][1]; st.z = sacc[ii][2]; st.w = sacc[ii][3];
      *(float4*)&part_l[base + (2*w+ii)*16 + lg*4] = st;
    }
  }
}

// =================================================================
// k_mix: round-8 proven version (Al dbuf, 1 barrier/tile, (512,4))
// =================================================================
__global__ __launch_bounds__(512,4) void k_mix(
    const unsigned short* __restrict__ Pb,
    const unsigned short* __restrict__ vt,
    const unsigned short* __restrict__ wpost_b,
    const float* __restrict__ bpost,
    const float* __restrict__ vsum,
    const float* __restrict__ part_l,
    float* __restrict__ pout0,
    float* __restrict__ pout1)
{
  __shared__ __align__(16) char smem[33792];
  float* linv = (float*)(smem + 32768);
  const int tid = threadIdx.x;
  const int w = tid>>6, lane = tid&63, lg = lane>>4, lp = lane&15;
  const int bid = blockIdx.x;
  const int qd = bid>>4, r2 = bid&15;
  const int b = r2>>3, n = qd*8 + (r2&7);
  const int it = n>>1, js = n&1;
  const int i0 = it*16, jsb = js*1024;

  if (tid < 256){
    int base = ((b*128+it)*4)*256 + tid;
    float sum = part_l[base] + part_l[base+256] + part_l[base+512] + part_l[base+768];
    linv[tid] = 1.f/sum;
  }
  __syncthreads();

  bf16x8 postB[2];
  #pragma unroll
  for (int ii=0;ii<2;++ii){
    postB[ii] = zerob();
    if (lg < 2){
      bf16x8 wf = *(const bf16x8*)&wpost_b[lp*16 + lg*8];
      int i = 2*w+ii;
      #pragma unroll
      for (int e=0;e<8;++e){
        float vsc = bf2f((unsigned short)wf[e]) * linv[i*16 + lg*8 + e];
        postB[ii][e] = (short)f2bf(vsc);
      }
    }
  }

  f32x4 oacc[2][4];
  #pragma unroll
  for (int hh=0; hh<2; ++hh)
    #pragma unroll
    for (int df=0; df<4; ++df) oacc[hh][df] = zero4();

  __syncthreads();

  for (int t=0; t<32; ++t){
    const int j0 = jsb + t*32;
    char* abuf = smem + (t&1)*16384;
    bf16x8 pfr[4];
    #pragma unroll
    for (int cc=0; cc<4; ++cc){
      int il = 2*w + (cc>>1);
      pfr[cc] = zerob();
      if (lg < 2)
        pfr[cc] = *(const bf16x8*)&Pb[(((size_t)(b*2048 + i0+il)*2048) + j0 + (cc&1)*16 + lp)*16 + lg*8];
    }
    bf16x8 vfr[2][4];
    #pragma unroll
    for (int hh=0; hh<2; ++hh)
      #pragma unroll
      for (int df=0; df<4; ++df)
        vfr[hh][df] = *(const bf16x8*)(vt + ((size_t)(b*16+2*w+hh)*64 + df*16 + lp)*2048 + j0 + lg*8);
    #pragma unroll
    for (int cc=0; cc<4; ++cc){
      int il = 2*w + (cc>>1);
      f32x4 aa = mfma16(pfr[cc], postB[cc>>1], zero4());
      short4v av;
      av.x = (short)f2bf(aa[0]); av.y = (short)f2bf(aa[1]);
      av.z = (short)f2bf(aa[2]); av.w = (short)f2bf(aa[3]);
      int row = lp*16 + il;
      int chunk = ((cc&1)*4 + lg) ^ ((lp ^ il)&6);
      *(short4v*)(abuf + row*64 + chunk*8) = av;
    }
    barw();
    #pragma unroll
    for (int hh=0; hh<2; ++hh){
      int gg = 2*w+hh;
      bf16x8 af = *(const bf16x8*)(abuf + (gg*16+lp)*64 + (((lg*2) ^ ((gg^lp)&6))*8));
      #pragma unroll
      for (int df=0; df<4; ++df)
        oacc[hh][df] = mfma16(af, vfr[hh][df], oacc[hh][df]);
    }
  }

  float* po = js ? pout1 : pout0;
  #pragma unroll
  for (int hh=0; hh<2; ++hh){
    int gg = 2*w+hh;
    float bp = (js==0) ? bpost[gg] : 0.f;
    #pragma unroll
    for (int df=0; df<4; ++df){
      int d = df*16+lp;
      float vs = vsum[(b*16+gg)*64 + d];
      #pragma unroll
      for (int r=0;r<4;++r){
        po[((size_t)b*2048 + i0 + lg*4 + r)*1024 + gg*64 + d] = oacc[hh][df][r] + bp*vs;
      }
    }
  }
}

// ------------- combine partial outputs -> bf16 attn_out -------------
__global__ __launch_bounds__(256) void k_combine(const float* __restrict__ p0, const float* __restrict__ p1,
                                                 unsigned short* __restrict__ ao){
  int i = blockIdx.x*256 + threadIdx.x;
  float4 a = ((const float4*)p0)[i];
  float4 c = ((const float4*)p1)[i];
  short4v o;
  o.x=(short)f2bf(a.x+c.x); o.y=(short)f2bf(a.y+c.y);
  o.z=(short)f2bf(a.z+c.z); o.w=(short)f2bf(a.w+c.w);
  ((short4v*)ao)[i] = o;
}

// ======================================================================
extern "C" void kernel_launch(void* const* d_in, const int* in_sizes, int n_in,
                              void* d_out, int out_size, void* d_ws, size_t ws_size,
                              hipStream_t stream)
{
  const float* x        = (const float*)d_in[0];
  const float* pos_bias = (const float*)d_in[1];
  const unsigned char* mask = (const unsigned char*)d_in[2];
  const float* Wqkv     = (const float*)d_in[3];
  const float* Wout     = (const float*)d_in[4];
  const float* Wpre     = (const float*)d_in[5];
  const float* bpre     = (const float*)d_in[6];
  const float* Wpost    = (const float*)d_in[7];
  const float* bpost    = (const float*)d_in[8];
  const float* temp     = (const float*)d_in[9];
  float* out = (float*)d_out;
  float* kv_out = out + 4194304;

  char* ws = (char*)d_ws;
  unsigned short* XB    = (unsigned short*)(ws + 0);
  unsigned short* WT    = (unsigned short*)(ws + 8388608);
  unsigned short* WOT   = (unsigned short*)(ws + 8388608);
  float*          PART_L= (float*)        (ws + 11534336);
  unsigned short* WPRE2 = (unsigned short*)(ws + 12583424);
  unsigned short* WPOST = (unsigned short*)(ws + 12583936);
  float*          VSUM  = (float*)        (ws + 12584448);
  float*          MASKF = (float*)        (ws + 12593152);
  unsigned short* QKV   = (unsigned short*)(ws + 14680064);
  unsigned short* VT    = (unsigned short*)(ws + 14680064);
  float*          POUT0 = (float*)        (ws + 23068672);
  unsigned short* Q     = (unsigned short*)(ws + 39845888);
  unsigned short* KB    = (unsigned short*)(ws + 48234496);
  unsigned short* VB    = (unsigned short*)(ws + 56623104);
  float*          POUT1 = (float*)        (ws + 56623104);
  unsigned short* PB    = (unsigned short*)(ws + 75497472);   // 268.4 MB
  unsigned short* EPB   = (unsigned short*)(ws + 343932928);  // 134.2 MB
  unsigned short* AO    = XB;

  k_f32_to_bf16<<<4096, 256, 0, stream>>>(x, XB, 1048576);
  k_convT<<<dim3(96,32), 256, 0, stream>>>(Wqkv, WT, 1024, 3072);
  k_gemm<0><<<dim3(24,32), 256, 0, stream>>>(XB, WT, (void*)QKV, 4096, 3072, 1024);
  k_split_norm<<<16384, 256, 0, stream>>>(QKV, Q, KB, VB, kv_out);
  k_transpose_v<<<dim3(32,32), 256, 0, stream>>>(VB, VT);
  k_vsum<<<32, 256, 0, stream>>>(VB, VSUM);
  k_prep<<<1, 256, 0, stream>>>(Wpre, Wpost, temp, WPRE2, WPOST);
  k_maskf<<<16, 256, 0, stream>>>(mask, MASKF);
  k_convT<<<dim3(32,32), 256, 0, stream>>>(Wout, WOT, 1024, 1024);

  k_pbexp<<<4096, 256, 0, stream>>>(pos_bias, EPB);
  k_score2<<<1024, 512, 0, stream>>>(Q, KB, EPB, MASKF, WPRE2, bpre, PB, PART_L);
  k_mix<<<512, 512, 0, stream>>>(PB, VT, WPOST, bpost, VSUM, PART_L, POUT0, POUT1);
  k_combine<<<4096, 256, 0, stream>>>(POUT0, POUT1, AO);
  k_gemm<1><<<dim3(8,32), 256, 0, stream>>>(AO, WOT, d_out, 4096, 1024, 1024);
}

// Round 15
// 521.361 us; speedup vs baseline: 1.2829x; 1.1130x over previous
//
#include <hip/hip_runtime.h>
#include <stdint.h>

typedef __attribute__((ext_vector_type(8))) short bf16x8;
typedef __attribute__((ext_vector_type(4))) float f32x4;
typedef __attribute__((ext_vector_type(4))) short short4v;

#define DEV __device__ __forceinline__
#define L2E 1.4426950408889634f

DEV float bf2f(unsigned short s){ union{unsigned int u; float f;} x; x.u = ((unsigned int)s)<<16; return x.f; }
DEV unsigned short f2bf(float f){ union{float f; unsigned int u;} x; x.f = f; x.u += 0x7fffu + ((x.u>>16)&1u); return (unsigned short)(x.u>>16); }

DEV f32x4 mfma16(bf16x8 a, bf16x8 b, f32x4 c){
  return __builtin_amdgcn_mfma_f32_16x16x32_bf16(a, b, c, 0, 0, 0);
}
DEV f32x4 zero4(){ f32x4 z; z[0]=0.f; z[1]=0.f; z[2]=0.f; z[3]=0.f; return z; }
DEV bf16x8 zerob(){ bf16x8 z; z[0]=0;z[1]=0;z[2]=0;z[3]=0;z[4]=0;z[5]=0;z[6]=0;z[7]=0; return z; }
DEV float fexp2(float x){ float r; asm volatile("v_exp_f32 %0, %1" : "=v"(r) : "v"(x)); return r; }
DEV void barw(){ asm volatile("s_waitcnt lgkmcnt(0)" ::: "memory"); __builtin_amdgcn_s_barrier(); }

// ---------------- elementwise f32 -> bf16 ----------------
__global__ __launch_bounds__(256) void k_f32_to_bf16(const float* __restrict__ in, unsigned short* __restrict__ out, int n4){
  int i = blockIdx.x*256 + threadIdx.x;
  if (i < n4){
    float4 v = ((const float4*)in)[i];
    short4v o; o.x=(short)f2bf(v.x); o.y=(short)f2bf(v.y); o.z=(short)f2bf(v.z); o.w=(short)f2bf(v.w);
    ((short4v*)out)[i] = o;
  }
}

// ------------- f32 [R][C] -> bf16 transposed [C][R] -------------
__global__ __launch_bounds__(256) void k_convT(const float* __restrict__ in, unsigned short* __restrict__ out, int R, int Cc){
  __shared__ float t[32][33];
  int c0 = blockIdx.x*32, r0 = blockIdx.y*32;
  int tid = threadIdx.x;
  int row = tid>>3, col4 = (tid&7)*4;
  float4 v = *(const float4*)&in[(size_t)(r0+row)*Cc + c0 + col4];
  t[row][col4+0]=v.x; t[row][col4+1]=v.y; t[row][col4+2]=v.z; t[row][col4+3]=v.w;
  __syncthreads();
  short4v o;
  o.x=(short)f2bf(t[col4+0][row]); o.y=(short)f2bf(t[col4+1][row]);
  o.z=(short)f2bf(t[col4+2][row]); o.w=(short)f2bf(t[col4+3][row]);
  *(short4v*)&out[(size_t)(c0+row)*R + r0 + col4] = o;
}

// ------------- small prep -------------
__global__ __launch_bounds__(256) void k_prep(const float* __restrict__ wpre, const float* __restrict__ wpost,
                                              const float* __restrict__ temp,
                                              unsigned short* __restrict__ wpre_t2,
                                              unsigned short* __restrict__ wpost_b){
  int t = threadIdx.x;
  float T = temp[0];
  wpre_t2[t] = f2bf(wpre[t]*T*L2E);
  wpost_b[t] = f2bf(wpost[t]);
}

// ------------- mask bytes -> f32 addend -------------
__global__ __launch_bounds__(256) void k_maskf(const unsigned char* __restrict__ mask, float* __restrict__ maskf){
  int i = blockIdx.x*256 + threadIdx.x;
  if (i < 4096) maskf[i] = mask[i] ? -1e30f : 0.f;
}

// ------------- GEMM -------------
template<int OUTF>
__global__ __launch_bounds__(256,2) void k_gemm(const unsigned short* __restrict__ A, const unsigned short* __restrict__ Bt,
                                                void* __restrict__ Cv, int M, int Nn, int K){
  __shared__ unsigned short As[128][72];
  __shared__ unsigned short Bs[128][72];
  int tid = threadIdx.x;
  int n0 = blockIdx.x*128, m0 = blockIdx.y*128;
  int w = tid>>6, lane = tid&63, lg = lane>>4, lp = lane&15;
  int wm = (w>>1)*64, wn = (w&1)*64;
  f32x4 acc[4][4];
  #pragma unroll
  for (int i=0;i<4;++i)
    #pragma unroll
    for (int j=0;j<4;++j) acc[i][j] = zero4();

  for (int kt=0; kt<K; kt+=64){
    #pragma unroll
    for (int cch=0; cch<4; ++cch){
      int e = tid + cch*256; int r = e>>3, cl = (e&7)*8;
      *(bf16x8*)&As[r][cl] = *(const bf16x8*)&A[(size_t)(m0+r)*K + kt + cl];
      *(bf16x8*)&Bs[r][cl] = *(const bf16x8*)&Bt[(size_t)(n0+r)*K + kt + cl];
    }
    __syncthreads();
    #pragma unroll
    for (int ks=0; ks<2; ++ks){
      bf16x8 a[4], b[4];
      #pragma unroll
      for (int mi=0; mi<4; ++mi) a[mi] = *(const bf16x8*)&As[wm+mi*16+lp][ks*32 + lg*8];
      #pragma unroll
      for (int ni=0; ni<4; ++ni) b[ni] = *(const bf16x8*)&Bs[wn+ni*16+lp][ks*32 + lg*8];
      #pragma unroll
      for (int mi=0; mi<4; ++mi)
        #pragma unroll
        for (int ni=0; ni<4; ++ni)
          acc[mi][ni] = mfma16(a[mi], b[ni], acc[mi][ni]);
    }
    __syncthreads();
  }
  #pragma unroll
  for (int mi=0; mi<4; ++mi)
    #pragma unroll
    for (int ni=0; ni<4; ++ni)
      #pragma unroll
      for (int r=0; r<4; ++r){
        int row = m0+wm+mi*16+lg*4+r, col = n0+wn+ni*16+lp;
        if (OUTF) ((float*)Cv)[(size_t)row*Nn+col] = acc[mi][ni][r];
        else ((unsigned short*)Cv)[(size_t)row*Nn+col] = f2bf(acc[mi][ni][r]);
      }
}

// ------------- split qkv, l2norm q/k -------------
__global__ __launch_bounds__(256) void k_split_norm(const unsigned short* __restrict__ qkv,
                                                    unsigned short* __restrict__ q, unsigned short* __restrict__ k,
                                                    unsigned short* __restrict__ v, float* __restrict__ kv_out){
  int w = threadIdx.x>>6, lane = threadIdx.x&63;
  int widx = blockIdx.x*4 + w;
  int h = widx & 15; int bn = widx >> 4;
  int b = bn >> 11; int n = bn & 2047;
  size_t base = (size_t)bn*3072 + h*192 + lane*3;
  float qv = bf2f(qkv[base]), kvv = bf2f(qkv[base+1]), vv = bf2f(qkv[base+2]);
  float nq = qv*qv, nk = kvv*kvv;
  #pragma unroll
  for (int m=1; m<64; m<<=1){ nq += __shfl_xor(nq, m); nk += __shfl_xor(nk, m); }
  float qn = qv / fmaxf(sqrtf(nq), 1e-12f);
  float kn = kvv / fmaxf(sqrtf(nk), 1e-12f);
  size_t idx = ((size_t)(b*16+h)*2048 + n)*64 + lane;
  q[idx] = f2bf(qn); k[idx] = f2bf(kn); v[idx] = f2bf(vv);
  kv_out[idx] = kn;
  kv_out[4194304 + idx] = vv;
}

// ------------- v -> vt transposed -------------
__global__ __launch_bounds__(256) void k_transpose_v(const unsigned short* __restrict__ v, unsigned short* __restrict__ vt){
  __shared__ unsigned short t[64][72];
  int bh = blockIdx.y; int n0 = blockIdx.x*64;
  int tid = threadIdx.x;
  #pragma unroll
  for (int cch=0; cch<2; ++cch){
    int e = tid + cch*256; int r = e>>3, c8 = (e&7)*8;
    *(bf16x8*)&t[r][c8] = *(const bf16x8*)&v[((size_t)bh*2048 + n0 + r)*64 + c8];
  }
  __syncthreads();
  #pragma unroll
  for (int cch=0; cch<2; ++cch){
    int e = tid + cch*256; int d = e>>3, nn8 = (e&7)*8;
    bf16x8 o;
    #pragma unroll
    for (int i=0;i<8;++i) o[i] = (short)t[nn8+i][d];
    *(bf16x8*)&vt[((size_t)bh*64 + d)*2048 + n0 + nn8] = o;
  }
}

// ------------- vsum -------------
__global__ __launch_bounds__(256) void k_vsum(const unsigned short* __restrict__ v, float* __restrict__ vsum){
  int bg = blockIdx.x;
  int d = threadIdx.x & 63, part = threadIdx.x>>6;
  float s = 0.f;
  for (int n = part*512; n < part*512+512; ++n) s += bf2f(v[((size_t)bg*2048 + n)*64 + d]);
  __shared__ float red[4][64];
  red[part][d] = s; __syncthreads();
  if (part==0) vsum[bg*64 + d] = red[0][d]+red[1][d]+red[2][d]+red[3][d];
}

// =================================================================
// k_score: round-8 proven version (f32 pos_bias in-tile, K one-ahead,
// S dbuf + 1 barrier/tile, (512,4), 64 regs no spill). grid 1024.
// =================================================================
__global__ __launch_bounds__(512,4) void k_score(
    const unsigned short* __restrict__ q,
    const unsigned short* __restrict__ kk,
    const float* __restrict__ pos_bias,
    const float* __restrict__ maskf,
    const unsigned short* __restrict__ wpre_t2,
    const float* __restrict__ bpre,
    unsigned short* __restrict__ Pb,
    float* __restrict__ part_l)
{
  __shared__ __align__(16) char smem[40960];
  const int tid = threadIdx.x;
  const int w = tid>>6, lane = tid&63, lg = lane>>4, lp = lane&15;
  const int bid = blockIdx.x;
  const int qd = bid>>4, r2 = bid&15;
  const int b = r2>>3, n = qd*8 + (r2&7);
  const int it = n>>2, js = n&3;
  const int i0 = it*16, jsb = js*512;

  bf16x8 qf[2][2];
  #pragma unroll
  for (int hh=0; hh<2; ++hh){
    const unsigned short* qb = q + ((size_t)(b*16+2*w+hh)*2048 + i0 + lp)*64;
    qf[hh][0] = *(const bf16x8*)(qb + lg*8);
    qf[hh][1] = *(const bf16x8*)(qb + 32 + lg*8);
  }
  bf16x8 preA = zerob();
  if (lg < 2) preA = *(const bf16x8*)&wpre_t2[lp*16 + lg*8];
  float bpre_s[4];
  #pragma unroll
  for (int r=0;r<4;++r) bpre_s[r] = bpre[lg*4+r]*L2E - 32.0f;

  float sacc[2][4];
  #pragma unroll
  for (int ii=0;ii<2;++ii)
    #pragma unroll
    for (int r=0;r<4;++r) sacc[ii][r] = 0.f;

  const size_t kbase0 = (size_t)(b*16 + 2*w)*131072;
  const size_t kbase1 = (size_t)(b*16 + 2*w+1)*131072;

  // prefetch K(0)
  bf16x8 k0v[4], k1v[4];
  #pragma unroll
  for (int kf=0; kf<2; ++kf)
    #pragma unroll
    for (int jf=0; jf<2; ++jf){
      size_t off = (size_t)(jsb + jf*16 + lp)*64 + kf*32 + lg*8;
      k0v[kf*2+jf] = *(const bf16x8*)(kk + kbase0 + off);
      k1v[kf*2+jf] = *(const bf16x8*)(kk + kbase1 + off);
    }

  for (int t=0; t<16; ++t){
    const int j0 = jsb + t*32;
    const int j0n = jsb + ((t+1)&15)*32;
    char* sbuf = smem + (t&1)*20480;
    // this tile's pos_bias + mask (issued first; consumed after barrier)
    float pbt[4][4];
    #pragma unroll
    for (int cc=0; cc<4; ++cc){
      int il = 2*w + (cc>>1);
      int jl = (cc&1)*16 + lp;
      #pragma unroll
      for (int r=0;r<4;++r)
        pbt[cc][r] = pos_bias[(size_t)(lg*4+r)*4194304 + (size_t)(i0+il)*2048 + j0 + jl];
    }
    float mk0 = maskf[b*2048 + j0 + lp];
    float mk1 = maskf[b*2048 + j0 + 16 + lp];

    // QK (K prefetched last tile)
    f32x4 s0[2], s1[2];
    #pragma unroll
    for (int jf=0;jf<2;++jf){ s0[jf]=zero4(); s1[jf]=zero4(); }
    #pragma unroll
    for (int kf=0; kf<2; ++kf)
      #pragma unroll
      for (int jf=0; jf<2; ++jf){
        s0[jf] = mfma16(qf[0][kf], k0v[kf*2+jf], s0[jf]);
        s1[jf] = mfma16(qf[1][kf], k1v[kf*2+jf], s1[jf]);
      }
    // S write (40B rows)
    #pragma unroll
    for (int jf=0;jf<2;++jf)
      #pragma unroll
      for (int r=0;r<4;++r){
        int ij = (lg*4+r)*32 + jf*16 + lp;
        unsigned int pk = (unsigned int)f2bf(s0[jf][r]) | ((unsigned int)f2bf(s1[jf][r])<<16);
        *(unsigned int*)(sbuf + ij*40 + w*4) = pk;
      }
    // K prefetch next tile
    #pragma unroll
    for (int kf=0; kf<2; ++kf)
      #pragma unroll
      for (int jf=0; jf<2; ++jf){
        size_t off = (size_t)(j0n + jf*16 + lp)*64 + kf*32 + lg*8;
        k0v[kf*2+jf] = *(const bf16x8*)(kk + kbase0 + off);
        k1v[kf*2+jf] = *(const bf16x8*)(kk + kbase1 + off);
      }
    barw();   // single barrier per tile (S dbuf)

    // premix + exp2 + Pb store
    #pragma unroll
    for (int cc=0; cc<4; ++cc){
      int c = w*4+cc;
      int il = 2*w + (cc>>1);
      int jl = (cc&1)*16 + lp;
      bf16x8 sfrag = zerob();
      if (lg < 2) sfrag = *(const bf16x8*)(sbuf + (c*16+lp)*40 + lg*16);
      f32x4 pa = mfma16(preA, sfrag, zero4());
      float mkj = (cc&1) ? mk1 : mk0;
      float pv0 = fexp2(fmaf(pbt[cc][0], L2E, pa[0] + bpre_s[0] + mkj));
      float pv1 = fexp2(fmaf(pbt[cc][1], L2E, pa[1] + bpre_s[1] + mkj));
      float pv2 = fexp2(fmaf(pbt[cc][2], L2E, pa[2] + bpre_s[2] + mkj));
      float pv3 = fexp2(fmaf(pbt[cc][3], L2E, pa[3] + bpre_s[3] + mkj));
      sacc[cc>>1][0] += pv0; sacc[cc>>1][1] += pv1;
      sacc[cc>>1][2] += pv2; sacc[cc>>1][3] += pv3;
      short4v p4;
      p4.x = (short)f2bf(pv0); p4.y = (short)f2bf(pv1);
      p4.z = (short)f2bf(pv2); p4.w = (short)f2bf(pv3);
      *(short4v*)&Pb[(((size_t)(b*2048 + i0+il)*2048) + j0 + jl)*16 + lg*4] = p4;
    }
  }

  #pragma unroll
  for (int ii=0;ii<2;++ii)
    #pragma unroll
    for (int r=0;r<4;++r){
      float v = sacc[ii][r];
      #pragma unroll
      for (int m=1; m<16; m<<=1) v += __shfl_xor(v, m);
      sacc[ii][r] = v;
    }
  if (lp == 0){
    int base = ((b*128+it)*4 + js)*256;
    #pragma unroll
    for (int ii=0;ii<2;++ii){
      float4 st; st.x = sacc[ii][0]; st.y = sacc[ii][1]; st.z = sacc[ii][2]; st.w = sacc[ii][3];
      *(float4*)&part_l[base + (2*w+ii)*16 + lg*4] = st;
    }
  }
}

// =================================================================
// k_mix: js-MERGED — full j sweep per block (64 tiles), f32 oacc,
// writes AO bf16 directly (no POUT round-trip, no combine kernel).
// grid 256: bid -> (b = bid&1, it = bid>>1). Al dbuf, 1 barrier/tile.
// =================================================================
__global__ __launch_bounds__(512,4) void k_mix(
    const unsigned short* __restrict__ Pb,
    const unsigned short* __restrict__ vt,
    const unsigned short* __restrict__ wpost_b,
    const float* __restrict__ bpost,
    const float* __restrict__ vsum,
    const float* __restrict__ part_l,
    unsigned short* __restrict__ ao)
{
  __shared__ __align__(16) char smem[33792];
  float* linv = (float*)(smem + 32768);
  const int tid = threadIdx.x;
  const int w = tid>>6, lane = tid&63, lg = lane>>4, lp = lane&15;
  const int bid = blockIdx.x;
  const int b = bid & 1, it = bid >> 1;
  const int i0 = it*16;

  if (tid < 256){
    int base = ((b*128+it)*4)*256 + tid;
    float sum = part_l[base] + part_l[base+256] + part_l[base+512] + part_l[base+768];
    linv[tid] = 1.f/sum;
  }
  __syncthreads();

  bf16x8 postB[2];
  #pragma unroll
  for (int ii=0;ii<2;++ii){
    postB[ii] = zerob();
    if (lg < 2){
      bf16x8 wf = *(const bf16x8*)&wpost_b[lp*16 + lg*8];
      int i = 2*w+ii;
      #pragma unroll
      for (int e=0;e<8;++e){
        float vsc = bf2f((unsigned short)wf[e]) * linv[i*16 + lg*8 + e];
        postB[ii][e] = (short)f2bf(vsc);
      }
    }
  }

  f32x4 oacc[2][4];
  #pragma unroll
  for (int hh=0; hh<2; ++hh)
    #pragma unroll
    for (int df=0; df<4; ++df) oacc[hh][df] = zero4();

  __syncthreads();

  for (int t=0; t<64; ++t){
    const int j0 = t*32;
    char* abuf = smem + (t&1)*16384;
    // Pb loads for this tile
    bf16x8 pfr[4];
    #pragma unroll
    for (int cc=0; cc<4; ++cc){
      int il = 2*w + (cc>>1);
      pfr[cc] = zerob();
      if (lg < 2)
        pfr[cc] = *(const bf16x8*)&Pb[(((size_t)(b*2048 + i0+il)*2048) + j0 + (cc&1)*16 + lp)*16 + lg*8];
    }
    // V loads for this tile (consumed after barrier)
    bf16x8 vfr[2][4];
    #pragma unroll
    for (int hh=0; hh<2; ++hh)
      #pragma unroll
      for (int df=0; df<4; ++df)
        vfr[hh][df] = *(const bf16x8*)(vt + ((size_t)(b*16+2*w+hh)*64 + df*16 + lp)*2048 + j0 + lg*8);
    // postmix -> Al
    #pragma unroll
    for (int cc=0; cc<4; ++cc){
      int il = 2*w + (cc>>1);
      f32x4 aa = mfma16(pfr[cc], postB[cc>>1], zero4());
      short4v av;
      av.x = (short)f2bf(aa[0]); av.y = (short)f2bf(aa[1]);
      av.z = (short)f2bf(aa[2]); av.w = (short)f2bf(aa[3]);
      int row = lp*16 + il;
      int chunk = ((cc&1)*4 + lg) ^ ((lp ^ il)&6);
      *(short4v*)(abuf + row*64 + chunk*8) = av;
    }
    barw();   // single barrier per tile (Al dbuf)
    // PV
    #pragma unroll
    for (int hh=0; hh<2; ++hh){
      int gg = 2*w+hh;
      bf16x8 af = *(const bf16x8*)(abuf + (gg*16+lp)*64 + (((lg*2) ^ ((gg^lp)&6))*8));
      #pragma unroll
      for (int df=0; df<4; ++df)
        oacc[hh][df] = mfma16(af, vfr[hh][df], oacc[hh][df]);
    }
  }

  // epilogue: + bpost[g]*Vsum, write bf16 AO directly
  #pragma unroll
  for (int hh=0; hh<2; ++hh){
    int gg = 2*w+hh;
    float bp = bpost[gg];
    #pragma unroll
    for (int df=0; df<4; ++df){
      int d = df*16+lp;
      float vs = vsum[(b*16+gg)*64 + d];
      #pragma unroll
      for (int r=0;r<4;++r){
        float o = oacc[hh][df][r] + bp*vs;
        ao[((size_t)(b*2048 + i0 + lg*4 + r))*1024 + gg*64 + d] = f2bf(o);
      }
    }
  }
}

// ======================================================================
extern "C" void kernel_launch(void* const* d_in, const int* in_sizes, int n_in,
                              void* d_out, int out_size, void* d_ws, size_t ws_size,
                              hipStream_t stream)
{
  const float* x        = (const float*)d_in[0];
  const float* pos_bias = (const float*)d_in[1];
  const unsigned char* mask = (const unsigned char*)d_in[2];
  const float* Wqkv     = (const float*)d_in[3];
  const float* Wout     = (const float*)d_in[4];
  const float* Wpre     = (const float*)d_in[5];
  const float* bpre     = (const float*)d_in[6];
  const float* Wpost    = (const float*)d_in[7];
  const float* bpost    = (const float*)d_in[8];
  const float* temp     = (const float*)d_in[9];
  float* out = (float*)d_out;
  float* kv_out = out + 4194304;

  char* ws = (char*)d_ws;
  unsigned short* XB    = (unsigned short*)(ws + 0);          // x bf16 -> AO later
  unsigned short* WT    = (unsigned short*)(ws + 8388608);
  unsigned short* WOT   = (unsigned short*)(ws + 8388608);
  float*          PART_L= (float*)        (ws + 11534336);
  unsigned short* WPRE2 = (unsigned short*)(ws + 12583424);
  unsigned short* WPOST = (unsigned short*)(ws + 12583936);
  float*          VSUM  = (float*)        (ws + 12584448);
  float*          MASKF = (float*)        (ws + 12593152);
  unsigned short* QKV   = (unsigned short*)(ws + 14680064);
  unsigned short* VT    = (unsigned short*)(ws + 14680064);
  unsigned short* Q     = (unsigned short*)(ws + 39845888);
  unsigned short* KB    = (unsigned short*)(ws + 48234496);
  unsigned short* VB    = (unsigned short*)(ws + 56623104);
  unsigned short* PB    = (unsigned short*)(ws + 75497472);   // 268.4 MB
  unsigned short* AO    = XB;

  k_f32_to_bf16<<<4096, 256, 0, stream>>>(x, XB, 1048576);
  k_convT<<<dim3(96,32), 256, 0, stream>>>(Wqkv, WT, 1024, 3072);
  k_gemm<0><<<dim3(24,32), 256, 0, stream>>>(XB, WT, (void*)QKV, 4096, 3072, 1024);
  k_split_norm<<<16384, 256, 0, stream>>>(QKV, Q, KB, VB, kv_out);
  k_transpose_v<<<dim3(32,32), 256, 0, stream>>>(VB, VT);
  k_vsum<<<32, 256, 0, stream>>>(VB, VSUM);
  k_prep<<<1, 256, 0, stream>>>(Wpre, Wpost, temp, WPRE2, WPOST);
  k_maskf<<<16, 256, 0, stream>>>(mask, MASKF);
  k_convT<<<dim3(32,32), 256, 0, stream>>>(Wout, WOT, 1024, 1024);

  k_score<<<1024, 512, 0, stream>>>(Q, KB, pos_bias, MASKF, WPRE2, bpre, PB, PART_L);
  k_mix<<<256, 512, 0, stream>>>(PB, VT, WPOST, bpost, VSUM, PART_L, AO);
  k_gemm<1><<<dim3(8,32), 256, 0, stream>>>(AO, WOT, d_out, 4096, 1024, 1024);
}

// Round 16
// 511.134 us; speedup vs baseline: 1.3086x; 1.0200x over previous
//
#include <hip/hip_runtime.h>
#include <stdint.h>

typedef __attribute__((ext_vector_type(8))) short bf16x8;
typedef __attribute__((ext_vector_type(4))) float f32x4;
typedef __attribute__((ext_vector_type(4))) short short4v;

#define DEV __device__ __forceinline__
#define L2E 1.4426950408889634f

DEV float bf2f(unsigned short s){ union{unsigned int u; float f;} x; x.u = ((unsigned int)s)<<16; return x.f; }
DEV unsigned short f2bf(float f){ union{float f; unsigned int u;} x; x.f = f; x.u += 0x7fffu + ((x.u>>16)&1u); return (unsigned short)(x.u>>16); }

DEV f32x4 mfma16(bf16x8 a, bf16x8 b, f32x4 c){
  return __builtin_amdgcn_mfma_f32_16x16x32_bf16(a, b, c, 0, 0, 0);
}
DEV f32x4 zero4(){ f32x4 z; z[0]=0.f; z[1]=0.f; z[2]=0.f; z[3]=0.f; return z; }
DEV bf16x8 zerob(){ bf16x8 z; z[0]=0;z[1]=0;z[2]=0;z[3]=0;z[4]=0;z[5]=0;z[6]=0;z[7]=0; return z; }
DEV float fexp2(float x){ float r; asm volatile("v_exp_f32 %0, %1" : "=v"(r) : "v"(x)); return r; }
DEV void barw(){ asm volatile("s_waitcnt lgkmcnt(0)" ::: "memory"); __builtin_amdgcn_s_barrier(); }

// ---------------- elementwise f32 -> bf16 ----------------
__global__ __launch_bounds__(256) void k_f32_to_bf16(const float* __restrict__ in, unsigned short* __restrict__ out, int n4){
  int i = blockIdx.x*256 + threadIdx.x;
  if (i < n4){
    float4 v = ((const float4*)in)[i];
    short4v o; o.x=(short)f2bf(v.x); o.y=(short)f2bf(v.y); o.z=(short)f2bf(v.z); o.w=(short)f2bf(v.w);
    ((short4v*)out)[i] = o;
  }
}

// ------------- f32 [R][C] -> bf16 transposed [C][R] -------------
__global__ __launch_bounds__(256) void k_convT(const float* __restrict__ in, unsigned short* __restrict__ out, int R, int Cc){
  __shared__ float t[32][33];
  int c0 = blockIdx.x*32, r0 = blockIdx.y*32;
  int tid = threadIdx.x;
  int row = tid>>3, col4 = (tid&7)*4;
  float4 v = *(const float4*)&in[(size_t)(r0+row)*Cc + c0 + col4];
  t[row][col4+0]=v.x; t[row][col4+1]=v.y; t[row][col4+2]=v.z; t[row][col4+3]=v.w;
  __syncthreads();
  short4v o;
  o.x=(short)f2bf(t[col4+0][row]); o.y=(short)f2bf(t[col4+1][row]);
  o.z=(short)f2bf(t[col4+2][row]); o.w=(short)f2bf(t[col4+3][row]);
  *(short4v*)&out[(size_t)(c0+row)*R + r0 + col4] = o;
}

// ------------- small prep -------------
__global__ __launch_bounds__(256) void k_prep(const float* __restrict__ wpre, const float* __restrict__ wpost,
                                              const float* __restrict__ temp,
                                              unsigned short* __restrict__ wpre_t2,
                                              unsigned short* __restrict__ wpost_b){
  int t = threadIdx.x;
  float T = temp[0];
  wpre_t2[t] = f2bf(wpre[t]*T*L2E);
  wpost_b[t] = f2bf(wpost[t]);
}

// ------------- mask bytes -> f32 addend -------------
__global__ __launch_bounds__(256) void k_maskf(const unsigned char* __restrict__ mask, float* __restrict__ maskf){
  int i = blockIdx.x*256 + threadIdx.x;
  if (i < 4096) maskf[i] = mask[i] ? -1e30f : 0.f;
}

// ------------- GEMM -------------
template<int OUTF>
__global__ __launch_bounds__(256,2) void k_gemm(const unsigned short* __restrict__ A, const unsigned short* __restrict__ Bt,
                                                void* __restrict__ Cv, int M, int Nn, int K){
  __shared__ unsigned short As[128][72];
  __shared__ unsigned short Bs[128][72];
  int tid = threadIdx.x;
  int n0 = blockIdx.x*128, m0 = blockIdx.y*128;
  int w = tid>>6, lane = tid&63, lg = lane>>4, lp = lane&15;
  int wm = (w>>1)*64, wn = (w&1)*64;
  f32x4 acc[4][4];
  #pragma unroll
  for (int i=0;i<4;++i)
    #pragma unroll
    for (int j=0;j<4;++j) acc[i][j] = zero4();

  for (int kt=0; kt<K; kt+=64){
    #pragma unroll
    for (int cch=0; cch<4; ++cch){
      int e = tid + cch*256; int r = e>>3, cl = (e&7)*8;
      *(bf16x8*)&As[r][cl] = *(const bf16x8*)&A[(size_t)(m0+r)*K + kt + cl];
      *(bf16x8*)&Bs[r][cl] = *(const bf16x8*)&Bt[(size_t)(n0+r)*K + kt + cl];
    }
    __syncthreads();
    #pragma unroll
    for (int ks=0; ks<2; ++ks){
      bf16x8 a[4], b[4];
      #pragma unroll
      for (int mi=0; mi<4; ++mi) a[mi] = *(const bf16x8*)&As[wm+mi*16+lp][ks*32 + lg*8];
      #pragma unroll
      for (int ni=0; ni<4; ++ni) b[ni] = *(const bf16x8*)&Bs[wn+ni*16+lp][ks*32 + lg*8];
      #pragma unroll
      for (int mi=0; mi<4; ++mi)
        #pragma unroll
        for (int ni=0; ni<4; ++ni)
          acc[mi][ni] = mfma16(a[mi], b[ni], acc[mi][ni]);
    }
    __syncthreads();
  }
  #pragma unroll
  for (int mi=0; mi<4; ++mi)
    #pragma unroll
    for (int ni=0; ni<4; ++ni)
      #pragma unroll
      for (int r=0; r<4; ++r){
        int row = m0+wm+mi*16+lg*4+r, col = n0+wn+ni*16+lp;
        if (OUTF) ((float*)Cv)[(size_t)row*Nn+col] = acc[mi][ni][r];
        else ((unsigned short*)Cv)[(size_t)row*Nn+col] = f2bf(acc[mi][ni][r]);
      }
}

// ------------- split qkv, l2norm q/k -------------
__global__ __launch_bounds__(256) void k_split_norm(const unsigned short* __restrict__ qkv,
                                                    unsigned short* __restrict__ q, unsigned short* __restrict__ k,
                                                    unsigned short* __restrict__ v, float* __restrict__ kv_out){
  int w = threadIdx.x>>6, lane = threadIdx.x&63;
  int widx = blockIdx.x*4 + w;
  int h = widx & 15; int bn = widx >> 4;
  int b = bn >> 11; int n = bn & 2047;
  size_t base = (size_t)bn*3072 + h*192 + lane*3;
  float qv = bf2f(qkv[base]), kvv = bf2f(qkv[base+1]), vv = bf2f(qkv[base+2]);
  float nq = qv*qv, nk = kvv*kvv;
  #pragma unroll
  for (int m=1; m<64; m<<=1){ nq += __shfl_xor(nq, m); nk += __shfl_xor(nk, m); }
  float qn = qv / fmaxf(sqrtf(nq), 1e-12f);
  float kn = kvv / fmaxf(sqrtf(nk), 1e-12f);
  size_t idx = ((size_t)(b*16+h)*2048 + n)*64 + lane;
  q[idx] = f2bf(qn); k[idx] = f2bf(kn); v[idx] = f2bf(vv);
  kv_out[idx] = kn;
  kv_out[4194304 + idx] = vv;
}

// ------------- v -> vt transposed -------------
__global__ __launch_bounds__(256) void k_transpose_v(const unsigned short* __restrict__ v, unsigned short* __restrict__ vt){
  __shared__ unsigned short t[64][72];
  int bh = blockIdx.y; int n0 = blockIdx.x*64;
  int tid = threadIdx.x;
  #pragma unroll
  for (int cch=0; cch<2; ++cch){
    int e = tid + cch*256; int r = e>>3, c8 = (e&7)*8;
    *(bf16x8*)&t[r][c8] = *(const bf16x8*)&v[((size_t)bh*2048 + n0 + r)*64 + c8];
  }
  __syncthreads();
  #pragma unroll
  for (int cch=0; cch<2; ++cch){
    int e = tid + cch*256; int d = e>>3, nn8 = (e&7)*8;
    bf16x8 o;
    #pragma unroll
    for (int i=0;i<8;++i) o[i] = (short)t[nn8+i][d];
    *(bf16x8*)&vt[((size_t)bh*64 + d)*2048 + n0 + nn8] = o;
  }
}

// ------------- vsum -------------
__global__ __launch_bounds__(256) void k_vsum(const unsigned short* __restrict__ v, float* __restrict__ vsum){
  int bg = blockIdx.x;
  int d = threadIdx.x & 63, part = threadIdx.x>>6;
  float s = 0.f;
  for (int n = part*512; n < part*512+512; ++n) s += bf2f(v[((size_t)bg*2048 + n)*64 + d]);
  __shared__ float red[4][64];
  red[part][d] = s; __syncthreads();
  if (part==0) vsum[bg*64 + d] = red[0][d]+red[1][d]+red[2][d]+red[3][d];
}

// =================================================================
// k_score: r15 version + nontemporal Pb stores (write-once stream).
// =================================================================
__global__ __launch_bounds__(512,4) void k_score(
    const unsigned short* __restrict__ q,
    const unsigned short* __restrict__ kk,
    const float* __restrict__ pos_bias,
    const float* __restrict__ maskf,
    const unsigned short* __restrict__ wpre_t2,
    const float* __restrict__ bpre,
    unsigned short* __restrict__ Pb,
    float* __restrict__ part_l)
{
  __shared__ __align__(16) char smem[40960];
  const int tid = threadIdx.x;
  const int w = tid>>6, lane = tid&63, lg = lane>>4, lp = lane&15;
  const int bid = blockIdx.x;
  const int qd = bid>>4, r2 = bid&15;
  const int b = r2>>3, n = qd*8 + (r2&7);
  const int it = n>>2, js = n&3;
  const int i0 = it*16, jsb = js*512;

  bf16x8 qf[2][2];
  #pragma unroll
  for (int hh=0; hh<2; ++hh){
    const unsigned short* qb = q + ((size_t)(b*16+2*w+hh)*2048 + i0 + lp)*64;
    qf[hh][0] = *(const bf16x8*)(qb + lg*8);
    qf[hh][1] = *(const bf16x8*)(qb + 32 + lg*8);
  }
  bf16x8 preA = zerob();
  if (lg < 2) preA = *(const bf16x8*)&wpre_t2[lp*16 + lg*8];
  float bpre_s[4];
  #pragma unroll
  for (int r=0;r<4;++r) bpre_s[r] = bpre[lg*4+r]*L2E - 32.0f;

  float sacc[2][4];
  #pragma unroll
  for (int ii=0;ii<2;++ii)
    #pragma unroll
    for (int r=0;r<4;++r) sacc[ii][r] = 0.f;

  const size_t kbase0 = (size_t)(b*16 + 2*w)*131072;
  const size_t kbase1 = (size_t)(b*16 + 2*w+1)*131072;

  // prefetch K(0)
  bf16x8 k0v[4], k1v[4];
  #pragma unroll
  for (int kf=0; kf<2; ++kf)
    #pragma unroll
    for (int jf=0; jf<2; ++jf){
      size_t off = (size_t)(jsb + jf*16 + lp)*64 + kf*32 + lg*8;
      k0v[kf*2+jf] = *(const bf16x8*)(kk + kbase0 + off);
      k1v[kf*2+jf] = *(const bf16x8*)(kk + kbase1 + off);
    }

  for (int t=0; t<16; ++t){
    const int j0 = jsb + t*32;
    const int j0n = jsb + ((t+1)&15)*32;
    char* sbuf = smem + (t&1)*20480;
    // this tile's pos_bias + mask (issued first; consumed after barrier)
    float pbt[4][4];
    #pragma unroll
    for (int cc=0; cc<4; ++cc){
      int il = 2*w + (cc>>1);
      int jl = (cc&1)*16 + lp;
      #pragma unroll
      for (int r=0;r<4;++r)
        pbt[cc][r] = pos_bias[(size_t)(lg*4+r)*4194304 + (size_t)(i0+il)*2048 + j0 + jl];
    }
    float mk0 = maskf[b*2048 + j0 + lp];
    float mk1 = maskf[b*2048 + j0 + 16 + lp];

    // QK (K prefetched last tile)
    f32x4 s0[2], s1[2];
    #pragma unroll
    for (int jf=0;jf<2;++jf){ s0[jf]=zero4(); s1[jf]=zero4(); }
    #pragma unroll
    for (int kf=0; kf<2; ++kf)
      #pragma unroll
      for (int jf=0; jf<2; ++jf){
        s0[jf] = mfma16(qf[0][kf], k0v[kf*2+jf], s0[jf]);
        s1[jf] = mfma16(qf[1][kf], k1v[kf*2+jf], s1[jf]);
      }
    // S write (40B rows)
    #pragma unroll
    for (int jf=0;jf<2;++jf)
      #pragma unroll
      for (int r=0;r<4;++r){
        int ij = (lg*4+r)*32 + jf*16 + lp;
        unsigned int pk = (unsigned int)f2bf(s0[jf][r]) | ((unsigned int)f2bf(s1[jf][r])<<16);
        *(unsigned int*)(sbuf + ij*40 + w*4) = pk;
      }
    // K prefetch next tile
    #pragma unroll
    for (int kf=0; kf<2; ++kf)
      #pragma unroll
      for (int jf=0; jf<2; ++jf){
        size_t off = (size_t)(j0n + jf*16 + lp)*64 + kf*32 + lg*8;
        k0v[kf*2+jf] = *(const bf16x8*)(kk + kbase0 + off);
        k1v[kf*2+jf] = *(const bf16x8*)(kk + kbase1 + off);
      }
    barw();   // single barrier per tile (S dbuf)

    // premix + exp2 + Pb store (nontemporal: write-once stream)
    #pragma unroll
    for (int cc=0; cc<4; ++cc){
      int c = w*4+cc;
      int il = 2*w + (cc>>1);
      int jl = (cc&1)*16 + lp;
      bf16x8 sfrag = zerob();
      if (lg < 2) sfrag = *(const bf16x8*)(sbuf + (c*16+lp)*40 + lg*16);
      f32x4 pa = mfma16(preA, sfrag, zero4());
      float mkj = (cc&1) ? mk1 : mk0;
      float pv0 = fexp2(fmaf(pbt[cc][0], L2E, pa[0] + bpre_s[0] + mkj));
      float pv1 = fexp2(fmaf(pbt[cc][1], L2E, pa[1] + bpre_s[1] + mkj));
      float pv2 = fexp2(fmaf(pbt[cc][2], L2E, pa[2] + bpre_s[2] + mkj));
      float pv3 = fexp2(fmaf(pbt[cc][3], L2E, pa[3] + bpre_s[3] + mkj));
      sacc[cc>>1][0] += pv0; sacc[cc>>1][1] += pv1;
      sacc[cc>>1][2] += pv2; sacc[cc>>1][3] += pv3;
      short4v p4;
      p4.x = (short)f2bf(pv0); p4.y = (short)f2bf(pv1);
      p4.z = (short)f2bf(pv2); p4.w = (short)f2bf(pv3);
      __builtin_nontemporal_store(p4,
        (short4v*)&Pb[(((size_t)(b*2048 + i0+il)*2048) + j0 + jl)*16 + lg*4]);
    }
  }

  #pragma unroll
  for (int ii=0;ii<2;++ii)
    #pragma unroll
    for (int r=0;r<4;++r){
      float v = sacc[ii][r];
      #pragma unroll
      for (int m=1; m<16; m<<=1) v += __shfl_xor(v, m);
      sacc[ii][r] = v;
    }
  if (lp == 0){
    int base = ((b*128+it)*4 + js)*256;
    #pragma unroll
    for (int ii=0;ii<2;++ii){
      float4 st; st.x = sacc[ii][0]; st.y = sacc[ii][1]; st.z = sacc[ii][2]; st.w = sacc[ii][3];
      *(float4*)&part_l[base + (2*w+ii)*16 + lg*4] = st;
    }
  }
}

// =================================================================
// k_mix: r15 merged version + nontemporal Pb loads (read-once stream).
// grid 256: bid -> (b = bid&1, it = bid>>1). Al dbuf, 1 barrier/tile.
// =================================================================
__global__ __launch_bounds__(512,4) void k_mix(
    const unsigned short* __restrict__ Pb,
    const unsigned short* __restrict__ vt,
    const unsigned short* __restrict__ wpost_b,
    const float* __restrict__ bpost,
    const float* __restrict__ vsum,
    const float* __restrict__ part_l,
    unsigned short* __restrict__ ao)
{
  __shared__ __align__(16) char smem[33792];
  float* linv = (float*)(smem + 32768);
  const int tid = threadIdx.x;
  const int w = tid>>6, lane = tid&63, lg = lane>>4, lp = lane&15;
  const int bid = blockIdx.x;
  const int b = bid & 1, it = bid >> 1;
  const int i0 = it*16;

  if (tid < 256){
    int base = ((b*128+it)*4)*256 + tid;
    float sum = part_l[base] + part_l[base+256] + part_l[base+512] + part_l[base+768];
    linv[tid] = 1.f/sum;
  }
  __syncthreads();

  bf16x8 postB[2];
  #pragma unroll
  for (int ii=0;ii<2;++ii){
    postB[ii] = zerob();
    if (lg < 2){
      bf16x8 wf = *(const bf16x8*)&wpost_b[lp*16 + lg*8];
      int i = 2*w+ii;
      #pragma unroll
      for (int e=0;e<8;++e){
        float vsc = bf2f((unsigned short)wf[e]) * linv[i*16 + lg*8 + e];
        postB[ii][e] = (short)f2bf(vsc);
      }
    }
  }

  f32x4 oacc[2][4];
  #pragma unroll
  for (int hh=0; hh<2; ++hh)
    #pragma unroll
    for (int df=0; df<4; ++df) oacc[hh][df] = zero4();

  __syncthreads();

  for (int t=0; t<64; ++t){
    const int j0 = t*32;
    char* abuf = smem + (t&1)*16384;
    // Pb loads for this tile (nontemporal: read-once stream)
    bf16x8 pfr[4];
    #pragma unroll
    for (int cc=0; cc<4; ++cc){
      int il = 2*w + (cc>>1);
      pfr[cc] = zerob();
      if (lg < 2)
        pfr[cc] = __builtin_nontemporal_load(
          (const bf16x8*)&Pb[(((size_t)(b*2048 + i0+il)*2048) + j0 + (cc&1)*16 + lp)*16 + lg*8]);
    }
    // V loads for this tile (consumed after barrier; L2-resident, normal)
    bf16x8 vfr[2][4];
    #pragma unroll
    for (int hh=0; hh<2; ++hh)
      #pragma unroll
      for (int df=0; df<4; ++df)
        vfr[hh][df] = *(const bf16x8*)(vt + ((size_t)(b*16+2*w+hh)*64 + df*16 + lp)*2048 + j0 + lg*8);
    // postmix -> Al
    #pragma unroll
    for (int cc=0; cc<4; ++cc){
      int il = 2*w + (cc>>1);
      f32x4 aa = mfma16(pfr[cc], postB[cc>>1], zero4());
      short4v av;
      av.x = (short)f2bf(aa[0]); av.y = (short)f2bf(aa[1]);
      av.z = (short)f2bf(aa[2]); av.w = (short)f2bf(aa[3]);
      int row = lp*16 + il;
      int chunk = ((cc&1)*4 + lg) ^ ((lp ^ il)&6);
      *(short4v*)(abuf + row*64 + chunk*8) = av;
    }
    barw();   // single barrier per tile (Al dbuf)
    // PV
    #pragma unroll
    for (int hh=0; hh<2; ++hh){
      int gg = 2*w+hh;
      bf16x8 af = *(const bf16x8*)(abuf + (gg*16+lp)*64 + (((lg*2) ^ ((gg^lp)&6))*8));
      #pragma unroll
      for (int df=0; df<4; ++df)
        oacc[hh][df] = mfma16(af, vfr[hh][df], oacc[hh][df]);
    }
  }

  // epilogue: + bpost[g]*Vsum, write bf16 AO directly
  #pragma unroll
  for (int hh=0; hh<2; ++hh){
    int gg = 2*w+hh;
    float bp = bpost[gg];
    #pragma unroll
    for (int df=0; df<4; ++df){
      int d = df*16+lp;
      float vs = vsum[(b*16+gg)*64 + d];
      #pragma unroll
      for (int r=0;r<4;++r){
        float o = oacc[hh][df][r] + bp*vs;
        ao[((size_t)(b*2048 + i0 + lg*4 + r))*1024 + gg*64 + d] = f2bf(o);
      }
    }
  }
}

// ======================================================================
extern "C" void kernel_launch(void* const* d_in, const int* in_sizes, int n_in,
                              void* d_out, int out_size, void* d_ws, size_t ws_size,
                              hipStream_t stream)
{
  const float* x        = (const float*)d_in[0];
  const float* pos_bias = (const float*)d_in[1];
  const unsigned char* mask = (const unsigned char*)d_in[2];
  const float* Wqkv     = (const float*)d_in[3];
  const float* Wout     = (const float*)d_in[4];
  const float* Wpre     = (const float*)d_in[5];
  const float* bpre     = (const float*)d_in[6];
  const float* Wpost    = (const float*)d_in[7];
  const float* bpost    = (const float*)d_in[8];
  const float* temp     = (const float*)d_in[9];
  float* out = (float*)d_out;
  float* kv_out = out + 4194304;

  char* ws = (char*)d_ws;
  unsigned short* XB    = (unsigned short*)(ws + 0);          // x bf16 -> AO later
  unsigned short* WT    = (unsigned short*)(ws + 8388608);
  unsigned short* WOT   = (unsigned short*)(ws + 8388608);
  float*          PART_L= (float*)        (ws + 11534336);
  unsigned short* WPRE2 = (unsigned short*)(ws + 12583424);
  unsigned short* WPOST = (unsigned short*)(ws + 12583936);
  float*          VSUM  = (float*)        (ws + 12584448);
  float*          MASKF = (float*)        (ws + 12593152);
  unsigned short* QKV   = (unsigned short*)(ws + 14680064);
  unsigned short* VT    = (unsigned short*)(ws + 14680064);
  unsigned short* Q     = (unsigned short*)(ws + 39845888);
  unsigned short* KB    = (unsigned short*)(ws + 48234496);
  unsigned short* VB    = (unsigned short*)(ws + 56623104);
  unsigned short* PB    = (unsigned short*)(ws + 75497472);   // 268.4 MB
  unsigned short* AO    = XB;

  k_f32_to_bf16<<<4096, 256, 0, stream>>>(x, XB, 1048576);
  k_convT<<<dim3(96,32), 256, 0, stream>>>(Wqkv, WT, 1024, 3072);
  k_gemm<0><<<dim3(24,32), 256, 0, stream>>>(XB, WT, (void*)QKV, 4096, 3072, 1024);
  k_split_norm<<<16384, 256, 0, stream>>>(QKV, Q, KB, VB, kv_out);
  k_transpose_v<<<dim3(32,32), 256, 0, stream>>>(VB, VT);
  k_vsum<<<32, 256, 0, stream>>>(VB, VSUM);
  k_prep<<<1, 256, 0, stream>>>(Wpre, Wpost, temp, WPRE2, WPOST);
  k_maskf<<<16, 256, 0, stream>>>(mask, MASKF);
  k_convT<<<dim3(32,32), 256, 0, stream>>>(Wout, WOT, 1024, 1024);

  k_score<<<1024, 512, 0, stream>>>(Q, KB, pos_bias, MASKF, WPRE2, bpre, PB, PART_L);
  k_mix<<<256, 512, 0, stream>>>(PB, VT, WPOST, bpost, VSUM, PART_L, AO);
  k_gemm<1><<<dim3(8,32), 256, 0, stream>>>(AO, WOT, d_out, 4096, 1024, 1024);
}